// Round 2
// baseline (852.489 us; speedup 1.0000x reference)
//
#include <hip/hip_runtime.h>

#define B 8
#define T 2048
#define C 96
#define NH 3
#define HD 32
#define FFD 2048
#define HALF_W 32
#define BT (B*T)

// ---------------- K1: QKV projection ----------------
// grid BT/32, block 256. qkv[b,t,o] = sum_c x[b,c,t]*w[o,c] + bias[o]
__global__ void qkv_kernel(const float* __restrict__ x, const float* __restrict__ w,
                           const float* __restrict__ bias, float* __restrict__ qkv){
    __shared__ float xs[C*33];     // [c][tt], padded stride 33
    __shared__ float wls[96*97];   // one 96-row third of w at a time, padded
    int blk = blockIdx.x;
    int b  = blk / (T/32);
    int t0 = (blk % (T/32)) * 32;
    for(int e = threadIdx.x; e < C*32; e += 256){
        int c = e/32, tt = e%32;
        xs[c*33 + tt] = x[(size_t)b*C*T + (size_t)c*T + t0 + tt];
    }
    for(int part = 0; part < 3; ++part){
        __syncthreads();   // guards xs (first iter) and wls reuse (later iters)
        for(int e = threadIdx.x; e < 96*96; e += 256)
            wls[(e/96)*97 + (e%96)] = w[(size_t)part*96*96 + e];
        __syncthreads();
        for(int idx = threadIdx.x; idx < 96*32; idx += 256){
            int o = idx % 96, tt = idx / 96;
            float acc = bias[part*96 + o];
            #pragma unroll 8
            for(int c = 0; c < 96; ++c)
                acc += wls[o*97 + c] * xs[c*33 + tt];
            qkv[((size_t)(b*T + t0 + tt))*288 + part*96 + o] = acc;
        }
    }
}

// ---------------- K2: banded attention ----------------
// grid B*NH*(T/128), block 128. One thread per query.
#define QT 128
#define KT (QT + 2*HALF_W)   // 192
__global__ void attn_kernel(const float* __restrict__ qkv, float* __restrict__ ctx){
    __shared__ float Ks[KT*33];
    __shared__ float Vs[KT*33];
    int blk = blockIdx.x;
    int ntile = T/QT;                 // 16
    int b   = blk / (NH*ntile);
    int rem = blk % (NH*ntile);
    int h   = rem / ntile;
    int t0  = (rem % ntile) * QT;
    for(int e = threadIdx.x; e < KT*HD; e += 128){
        int i = e/HD, d = e%HD;
        int s = t0 - HALF_W + i;
        float kv = 0.f, vv = 0.f;
        if(s >= 0 && s < T){
            const float* row = qkv + ((size_t)(b*T + s))*288 + h*HD;
            kv = row[96  + d];
            vv = row[192 + d];
        }
        Ks[i*33 + d] = kv;
        Vs[i*33 + d] = vv;
    }
    __syncthreads();
    int t = t0 + threadIdx.x;
    float q[HD];
    {
        const float* qrow = qkv + ((size_t)(b*T + t))*288 + h*HD;
        #pragma unroll
        for(int d = 0; d < HD; ++d) q[d] = qrow[d];
    }
    const float scale = 0.17677669529663687f;   // 1/sqrt(32)
    float m = -1e30f;
    for(int k = 0; k <= 2*HALF_W; ++k){
        int s = t - HALF_W + k;
        if(s < 0 || s >= T) continue;
        int li = threadIdx.x + k;
        float sc = 0.f;
        #pragma unroll
        for(int d = 0; d < HD; ++d) sc += q[d]*Ks[li*33 + d];
        m = fmaxf(m, sc*scale);
    }
    float l = 0.f;
    float o[HD];
    #pragma unroll
    for(int d = 0; d < HD; ++d) o[d] = 0.f;
    for(int k = 0; k <= 2*HALF_W; ++k){
        int s = t - HALF_W + k;
        if(s < 0 || s >= T) continue;
        int li = threadIdx.x + k;
        float sc = 0.f;
        #pragma unroll
        for(int d = 0; d < HD; ++d) sc += q[d]*Ks[li*33 + d];
        float p = __expf(sc*scale - m);
        l += p;
        #pragma unroll
        for(int d = 0; d < HD; ++d) o[d] += p*Vs[li*33 + d];
    }
    float inv = 1.0f/l;
    float* crow = ctx + ((size_t)(b*T + t))*96 + h*HD;
    #pragma unroll
    for(int d = 0; d < HD; ++d) crow[d] = o[d]*inv;
}

// ---------------- K3: output projection + residual ----------------
// grid BT/32, block 256. h1pre[row,c] = x[b,c,t] + b_out[c] + sum_k ctx[row,k]*w[c,k]
__global__ void outproj_kernel(const float* __restrict__ ctx, const float* __restrict__ w,
                               const float* __restrict__ bias, const float* __restrict__ x,
                               float* __restrict__ h1pre){
    __shared__ float cs[32*97];
    __shared__ float wls[96*97];
    int r0 = blockIdx.x*32;
    for(int e = threadIdx.x; e < 32*96; e += 256){
        int r = e/96, c = e%96;
        cs[r*97 + c] = ctx[(size_t)(r0 + r)*96 + c];
    }
    for(int e = threadIdx.x; e < 96*96; e += 256){
        wls[(e/96)*97 + (e%96)] = w[e];
    }
    __syncthreads();
    int rr = threadIdx.x/8;      // 0..31
    int cg = threadIdx.x%8;      // 0..7 (12 cols each)
    float acc[12];
    #pragma unroll
    for(int i = 0; i < 12; ++i) acc[i] = 0.f;
    for(int k = 0; k < 96; ++k){
        float cv = cs[rr*97 + k];
        #pragma unroll
        for(int i = 0; i < 12; ++i)
            acc[i] += cv * wls[(cg*12 + i)*97 + k];
    }
    int row = r0 + rr;
    int b = row / T, t = row % T;
    #pragma unroll
    for(int i = 0; i < 12; ++i){
        int c = cg*12 + i;
        h1pre[(size_t)row*96 + c] = acc[i] + bias[c]
                                  + x[(size_t)b*C*T + (size_t)c*T + t];
    }
}

// ---------------- K4: generic row LayerNorm fp32->fp32 ----------------
// grid BT/4, block 256 (wave per row).
__global__ void ln_kernel(const float* __restrict__ in, const float* __restrict__ g,
                          const float* __restrict__ bb, float* __restrict__ out){
    int wave = threadIdx.x/64, lane = threadIdx.x%64;
    size_t row = (size_t)blockIdx.x*4 + wave;
    const float* p = in + row*96;
    float v0 = p[lane];
    float v1 = (lane < 32) ? p[64 + lane] : 0.f;
    float s = v0 + v1;
    for(int off = 32; off; off >>= 1) s += __shfl_down(s, off);
    s = __shfl(s, 0);
    float mu = s*(1.0f/96.0f);
    float d0 = v0 - mu, d1 = (lane < 32) ? (v1 - mu) : 0.f;
    float q = d0*d0 + d1*d1;
    for(int off = 32; off; off >>= 1) q += __shfl_down(q, off);
    q = __shfl(q, 0);
    float rstd = rsqrtf(q*(1.0f/96.0f) + 1e-5f);
    float* po = out + row*96;
    po[lane] = d0*rstd*g[lane] + bb[lane];
    if(lane < 32)
        po[64 + lane] = d1*rstd*g[64 + lane] + bb[64 + lane];
}

// ---------------- K5: fused FF1+ReLU+FF2 + residual ----------------
// grid BT/32, block 256. h2pre = h1 + (relu(h1@w1^T + b1) @ w2^T + b2)
// j-tile = 64: LDS 70.5 KB -> 2 blocks/CU
__global__ void ff_kernel(const float* __restrict__ h1, const float* __restrict__ w1,
                          const float* __restrict__ b1, const float* __restrict__ w2,
                          const float* __restrict__ b2, float* __restrict__ h2pre){
    __shared__ float hs[32*97];
    __shared__ float w1t[64*97];
    __shared__ float ss[32*65];
    __shared__ float w2t[96*65];
    int r0 = blockIdx.x*32;
    for(int e = threadIdx.x; e < 32*96; e += 256){
        int r = e/96, c = e%96;
        hs[r*97 + c] = h1[(size_t)(r0 + r)*96 + c];
    }
    int rB = threadIdx.x/8, cg = threadIdx.x%8;   // phase-B mapping
    float acc[12];
    #pragma unroll
    for(int i = 0; i < 12; ++i) acc[i] = 0.f;
    int jj = threadIdx.x % 64, rg = threadIdx.x/64;  // phase-A mapping
    for(int j0 = 0; j0 < FFD; j0 += 64){
        __syncthreads();   // guards hs (1st iter) + w1t/w2t/ss reuse vs phase B reads
        for(int e = threadIdx.x; e < 64*96; e += 256){
            int j = e/96, c = e%96;
            w1t[j*97 + c] = w1[(size_t)(j0 + j)*96 + c];
        }
        for(int e = threadIdx.x; e < 96*64; e += 256){
            int c = e/64, j = e%64;
            w2t[c*65 + j] = w2[(size_t)c*FFD + j0 + j];
        }
        __syncthreads();
        // phase A: s[32][64] = hs @ w1tile^T, each thread: 8 rows x 1 col
        float s[8];
        #pragma unroll
        for(int i = 0; i < 8; ++i) s[i] = 0.f;
        for(int c = 0; c < 96; ++c){
            float wv = w1t[jj*97 + c];
            #pragma unroll
            for(int i = 0; i < 8; ++i)
                s[i] += hs[(rg*8 + i)*97 + c] * wv;
        }
        float bj = b1[j0 + jj];
        #pragma unroll
        for(int i = 0; i < 8; ++i){
            float v = s[i] + bj;
            ss[(rg*8 + i)*65 + jj] = v > 0.f ? v : 0.f;
        }
        __syncthreads();
        // phase B: acc += relu(s) @ w2tile^T
        for(int j = 0; j < 64; ++j){
            float sv = ss[rB*65 + j];
            #pragma unroll
            for(int i = 0; i < 12; ++i)
                acc[i] += sv * w2t[(cg*12 + i)*65 + j];
        }
    }
    int row = r0 + rB;
    #pragma unroll
    for(int i = 0; i < 12; ++i){
        int c = cg*12 + i;
        h2pre[(size_t)row*96 + c] = acc[i] + b2[c] + h1[(size_t)row*96 + c];
    }
}

// ---------------- K6: LN2 -> LNf -> transpose -> fp32 out ----------------
// grid BT/64, block 256 (4 waves x 16 rows each)
__global__ void ln2f_kernel(const float* __restrict__ in, const float* __restrict__ g2,
                            const float* __restrict__ bt2, const float* __restrict__ gf,
                            const float* __restrict__ btf, float* __restrict__ out){
    __shared__ float zt[96*65];   // [c][tt]
    int wave = threadIdx.x/64, lane = threadIdx.x%64;
    int r0 = blockIdx.x*64;
    for(int rw = 0; rw < 16; ++rw){
        int tt = wave*16 + rw;
        size_t row = (size_t)r0 + tt;
        const float* p = in + row*96;
        float v0 = p[lane];
        float v1 = (lane < 32) ? p[64 + lane] : 0.f;
        float s = v0 + v1;
        for(int off = 32; off; off >>= 1) s += __shfl_down(s, off);
        s = __shfl(s, 0);
        float mu = s*(1.0f/96.0f);
        float d0 = v0 - mu, d1 = (lane < 32) ? (v1 - mu) : 0.f;
        float q = d0*d0 + d1*d1;
        for(int off = 32; off; off >>= 1) q += __shfl_down(q, off);
        q = __shfl(q, 0);
        float rstd = rsqrtf(q*(1.0f/96.0f) + 1e-5f);
        float y0 = d0*rstd*g2[lane] + bt2[lane];
        float y1 = (lane < 32) ? (d1*rstd*g2[64 + lane] + bt2[64 + lane]) : 0.f;
        // LNf
        s = y0 + y1;
        for(int off = 32; off; off >>= 1) s += __shfl_down(s, off);
        s = __shfl(s, 0);
        mu = s*(1.0f/96.0f);
        d0 = y0 - mu; d1 = (lane < 32) ? (y1 - mu) : 0.f;
        q = d0*d0 + d1*d1;
        for(int off = 32; off; off >>= 1) q += __shfl_down(q, off);
        q = __shfl(q, 0);
        rstd = rsqrtf(q*(1.0f/96.0f) + 1e-5f);
        zt[lane*65 + tt] = d0*rstd*gf[lane] + btf[lane];
        if(lane < 32)
            zt[(64 + lane)*65 + tt] = d1*rstd*gf[64 + lane] + btf[64 + lane];
    }
    __syncthreads();
    int b  = r0 / T;
    int t0 = r0 % T;
    for(int e = threadIdx.x; e < 96*64; e += 256){
        int c = e/64, tt = e%64;
        out[(size_t)b*C*T + (size_t)c*T + t0 + tt] = zt[c*65 + tt];
    }
}

extern "C" void kernel_launch(void* const* d_in, const int* in_sizes, int n_in,
                              void* d_out, int out_size, void* d_ws, size_t ws_size,
                              hipStream_t stream) {
    const float* x     = (const float*)d_in[0];
    const float* w_qkv = (const float*)d_in[1];
    const float* b_qkv = (const float*)d_in[2];
    const float* w_out = (const float*)d_in[3];
    const float* b_out = (const float*)d_in[4];
    const float* ln1_g = (const float*)d_in[5];
    const float* ln1_b = (const float*)d_in[6];
    const float* w_ff1 = (const float*)d_in[7];
    const float* b_ff1 = (const float*)d_in[8];
    const float* w_ff2 = (const float*)d_in[9];
    const float* b_ff2 = (const float*)d_in[10];
    const float* ln2_g = (const float*)d_in[11];
    const float* ln2_b = (const float*)d_in[12];
    const float* lnf_g = (const float*)d_in[13];
    const float* lnf_b = (const float*)d_in[14];
    float* out = (float*)d_out;

    // Workspace layout with region reuse (peak = BT*384 floats = 25.2 MB):
    //   [0, BT*288)            qkv      (dead after attn)
    //   [BT*288, BT*384)       ctx      (dead after outproj)
    //   [0, BT*96)             h1pre    (reuses qkv; dead after ln)
    //   [BT*96, BT*192)        h1       (reuses qkv)
    //   [BT*192, BT*288)       h2pre    (reuses qkv)
    float* ws    = (float*)d_ws;
    float* qkv   = ws;
    float* ctx   = ws + (size_t)BT*288;
    float* h1pre = ws;
    float* h1    = ws + (size_t)BT*96;
    float* h2pre = ws + (size_t)BT*192;

    qkv_kernel    <<<BT/32, 256, 0, stream>>>(x, w_qkv, b_qkv, qkv);
    attn_kernel   <<<B*NH*(T/QT), 128, 0, stream>>>(qkv, ctx);
    outproj_kernel<<<BT/32, 256, 0, stream>>>(ctx, w_out, b_out, x, h1pre);
    ln_kernel     <<<BT/4, 256, 0, stream>>>(h1pre, ln1_g, ln1_b, h1);
    ff_kernel     <<<BT/32, 256, 0, stream>>>(h1, w_ff1, b_ff1, w_ff2, b_ff2, h2pre);
    ln2f_kernel   <<<BT/64, 256, 0, stream>>>(h2pre, ln2_g, ln2_b, lnf_g, lnf_b, out);
}

// Round 3
// 347.347 us; speedup vs baseline: 2.4543x; 2.4543x over previous
//
#include <hip/hip_runtime.h>
#include <hip/hip_bf16.h>

#define B 8
#define T 2048
#define C 96
#define NH 3
#define HD 32
#define FFD 2048
#define HALF_W 32
#define BT (B*T)

typedef __hip_bfloat16 bf16;
typedef __attribute__((ext_vector_type(8))) short short8;
typedef __attribute__((ext_vector_type(4))) short short4v;
typedef __attribute__((ext_vector_type(16))) float floatx16;

__device__ __forceinline__ short f2bs(float v){
    __hip_bfloat16 h = __float2bfloat16(v);
    return *reinterpret_cast<short*>(&h);
}

// ---------------- K1: QKV projection (fp32 vector, unchanged) ----------------
__global__ void qkv_kernel(const float* __restrict__ x, const float* __restrict__ w,
                           const float* __restrict__ bias, float* __restrict__ qkv){
    __shared__ float xs[C*33];
    __shared__ float wls[96*97];
    int blk = blockIdx.x;
    int b  = blk / (T/32);
    int t0 = (blk % (T/32)) * 32;
    for(int e = threadIdx.x; e < C*32; e += 256){
        int c = e/32, tt = e%32;
        xs[c*33 + tt] = x[(size_t)b*C*T + (size_t)c*T + t0 + tt];
    }
    for(int part = 0; part < 3; ++part){
        __syncthreads();
        for(int e = threadIdx.x; e < 96*96; e += 256)
            wls[(e/96)*97 + (e%96)] = w[(size_t)part*96*96 + e];
        __syncthreads();
        for(int idx = threadIdx.x; idx < 96*32; idx += 256){
            int o = idx % 96, tt = idx / 96;
            float acc = bias[part*96 + o];
            #pragma unroll 8
            for(int c = 0; c < 96; ++c)
                acc += wls[o*97 + c] * xs[c*33 + tt];
            qkv[((size_t)(b*T + t0 + tt))*288 + part*96 + o] = acc;
        }
    }
}

// ---------------- K2: banded attention (unchanged) ----------------
#define QT 128
#define KT (QT + 2*HALF_W)   // 192
__global__ void attn_kernel(const float* __restrict__ qkv, float* __restrict__ ctx){
    __shared__ float Ks[KT*33];
    __shared__ float Vs[KT*33];
    int blk = blockIdx.x;
    int ntile = T/QT;
    int b   = blk / (NH*ntile);
    int rem = blk % (NH*ntile);
    int h   = rem / ntile;
    int t0  = (rem % ntile) * QT;
    for(int e = threadIdx.x; e < KT*HD; e += 128){
        int i = e/HD, d = e%HD;
        int s = t0 - HALF_W + i;
        float kv = 0.f, vv = 0.f;
        if(s >= 0 && s < T){
            const float* row = qkv + ((size_t)(b*T + s))*288 + h*HD;
            kv = row[96  + d];
            vv = row[192 + d];
        }
        Ks[i*33 + d] = kv;
        Vs[i*33 + d] = vv;
    }
    __syncthreads();
    int t = t0 + threadIdx.x;
    float q[HD];
    {
        const float* qrow = qkv + ((size_t)(b*T + t))*288 + h*HD;
        #pragma unroll
        for(int d = 0; d < HD; ++d) q[d] = qrow[d];
    }
    const float scale = 0.17677669529663687f;
    float m = -1e30f;
    for(int k = 0; k <= 2*HALF_W; ++k){
        int s = t - HALF_W + k;
        if(s < 0 || s >= T) continue;
        int li = threadIdx.x + k;
        float sc = 0.f;
        #pragma unroll
        for(int d = 0; d < HD; ++d) sc += q[d]*Ks[li*33 + d];
        m = fmaxf(m, sc*scale);
    }
    float l = 0.f;
    float o[HD];
    #pragma unroll
    for(int d = 0; d < HD; ++d) o[d] = 0.f;
    for(int k = 0; k <= 2*HALF_W; ++k){
        int s = t - HALF_W + k;
        if(s < 0 || s >= T) continue;
        int li = threadIdx.x + k;
        float sc = 0.f;
        #pragma unroll
        for(int d = 0; d < HD; ++d) sc += q[d]*Ks[li*33 + d];
        float p = __expf(sc*scale - m);
        l += p;
        #pragma unroll
        for(int d = 0; d < HD; ++d) o[d] += p*Vs[li*33 + d];
    }
    float inv = 1.0f/l;
    float* crow = ctx + ((size_t)(b*T + t))*96 + h*HD;
    #pragma unroll
    for(int d = 0; d < HD; ++d) crow[d] = o[d]*inv;
}

// ---------------- K3: output projection + residual (unchanged) ----------------
__global__ void outproj_kernel(const float* __restrict__ ctx, const float* __restrict__ w,
                               const float* __restrict__ bias, const float* __restrict__ x,
                               float* __restrict__ h1pre){
    __shared__ float cs[32*97];
    __shared__ float wls[96*97];
    int r0 = blockIdx.x*32;
    for(int e = threadIdx.x; e < 32*96; e += 256){
        int r = e/96, c = e%96;
        cs[r*97 + c] = ctx[(size_t)(r0 + r)*96 + c];
    }
    for(int e = threadIdx.x; e < 96*96; e += 256){
        wls[(e/96)*97 + (e%96)] = w[e];
    }
    __syncthreads();
    int rr = threadIdx.x/8;
    int cg = threadIdx.x%8;
    float acc[12];
    #pragma unroll
    for(int i = 0; i < 12; ++i) acc[i] = 0.f;
    for(int k = 0; k < 96; ++k){
        float cv = cs[rr*97 + k];
        #pragma unroll
        for(int i = 0; i < 12; ++i)
            acc[i] += cv * wls[(cg*12 + i)*97 + k];
    }
    int row = r0 + rr;
    int b = row / T, t = row % T;
    #pragma unroll
    for(int i = 0; i < 12; ++i){
        int c = cg*12 + i;
        h1pre[(size_t)row*96 + c] = acc[i] + bias[c]
                                  + x[(size_t)b*C*T + (size_t)c*T + t];
    }
}

// ---------------- K3b: convert FF weights to bf16 ----------------
__global__ void cvtw_kernel(const float* __restrict__ w1, const float* __restrict__ w2,
                            bf16* __restrict__ w1b, bf16* __restrict__ w2b){
    int i = blockIdx.x*256 + threadIdx.x;
    if(i < FFD*C){
        w1b[i] = __float2bfloat16(w1[i]);
        w2b[i] = __float2bfloat16(w2[i]);
    }
}

// ---------------- K4: LayerNorm fp32->fp32 + bf16 copy ----------------
__global__ void ln_kernel(const float* __restrict__ in, const float* __restrict__ g,
                          const float* __restrict__ bb, float* __restrict__ out,
                          bf16* __restrict__ outb){
    int wave = threadIdx.x/64, lane = threadIdx.x%64;
    size_t row = (size_t)blockIdx.x*4 + wave;
    const float* p = in + row*96;
    float v0 = p[lane];
    float v1 = (lane < 32) ? p[64 + lane] : 0.f;
    float s = v0 + v1;
    for(int off = 32; off; off >>= 1) s += __shfl_down(s, off);
    s = __shfl(s, 0);
    float mu = s*(1.0f/96.0f);
    float d0 = v0 - mu, d1 = (lane < 32) ? (v1 - mu) : 0.f;
    float q = d0*d0 + d1*d1;
    for(int off = 32; off; off >>= 1) q += __shfl_down(q, off);
    q = __shfl(q, 0);
    float rstd = rsqrtf(q*(1.0f/96.0f) + 1e-5f);
    float* po = out + row*96;
    bf16* pb = outb + row*96;
    float y0 = d0*rstd*g[lane] + bb[lane];
    po[lane] = y0;
    pb[lane] = __float2bfloat16(y0);
    if(lane < 32){
        float y1 = d1*rstd*g[64 + lane] + bb[64 + lane];
        po[64 + lane] = y1;
        pb[64 + lane] = __float2bfloat16(y1);
    }
}

// ---------------- K5: MFMA fused FF1+ReLU+FF2 + residual ----------------
// M_BLK=64 rows/block, j-tile=128, mfma_f32_32x32x16_bf16.
// FF1: swapped operands (A=w1 rows, B=h rows) -> D[j][m]; C-layout reg quads are
// 4 consecutive j -> b64-pack into ss[m][j]. FF2: (A=w2 rows, B=s rows) -> D[c][m];
// waves split FF2 K-steps, reduced via LDS in epilogue.
__global__ __launch_bounds__(256) void ff_kernel(
    const bf16* __restrict__ h1b, const float* __restrict__ h1,
    const bf16* __restrict__ w1b, const float* __restrict__ b1,
    const bf16* __restrict__ w2b, const float* __restrict__ b2,
    float* __restrict__ h2pre){
    __shared__ __align__(16) char smem[26624 + 26112 + 17408];
    bf16* w1t = (bf16*)smem;                          // [128][104]
    bf16* w2t = (bf16*)(smem + 26624);                // [96][136]
    bf16* sst = (bf16*)(smem + 26624 + 26112);        // [64][136]
    float* red = (float*)smem;                        // epilogue reduction (overlaps w1t)

    const int tid = threadIdx.x;
    const int w = tid >> 6, lane = tid & 63;
    const int lm = lane & 31, hq = lane >> 5;
    const int r0 = blockIdx.x * 64;
    const int mt2 = w & 1, kh = w >> 1;

    // h fragments in registers: h1b[row][k], row = r0+mt*32+lm, k = ks*16+hq*8 (+0..7)
    short8 hf[2][6];
    #pragma unroll
    for(int mt = 0; mt < 2; ++mt)
        #pragma unroll
        for(int ks = 0; ks < 6; ++ks)
            hf[mt][ks] = *(const short8*)((const short*)h1b
                          + (size_t)(r0 + mt*32 + lm)*96 + ks*16 + hq*8);

    floatx16 acc2[3];
    #pragma unroll
    for(int i = 0; i < 3; ++i)
        #pragma unroll
        for(int r = 0; r < 16; ++r) acc2[i][r] = 0.f;

    for(int jt = 0; jt < 16; ++jt){
        const int j0 = jt * 128;
        __syncthreads();   // prev FF2 done with sst/w2t; FF1 done with w1t
        // stage w1 tile (128x96) -> w1t, w2 tile (96x128) -> w2t (bf16, 16B chunks)
        #pragma unroll
        for(int i = 0; i < 6; ++i){
            int e = tid + i*256;           // 1536 chunks
            int row = e/12, c8 = e%12;
            uint4 v = *(const uint4*)((const short*)w1b + (size_t)(j0+row)*96 + c8*8);
            *(uint4*)((short*)w1t + row*104 + c8*8) = v;
        }
        #pragma unroll
        for(int i = 0; i < 6; ++i){
            int e = tid + i*256;           // 1536 chunks
            int row = e/16, j8 = e%16;
            uint4 v = *(const uint4*)((const short*)w2b + (size_t)row*FFD + j0 + j8*8);
            *(uint4*)((short*)w2t + row*136 + j8*8) = v;
        }
        __syncthreads();
        // ---- FF1: wave w owns n-tile = j columns [w*32, w*32+32), both m-tiles
        floatx16 a0, a1;
        #pragma unroll
        for(int r = 0; r < 16; ++r){ a0[r] = 0.f; a1[r] = 0.f; }
        #pragma unroll
        for(int ks = 0; ks < 6; ++ks){
            short8 wf = *(const short8*)((const short*)w1t + (w*32+lm)*104 + ks*16 + hq*8);
            a0 = __builtin_amdgcn_mfma_f32_32x32x16_bf16(wf, hf[0][ks], a0, 0, 0, 0);
            a1 = __builtin_amdgcn_mfma_f32_32x32x16_bf16(wf, hf[1][ks], a1, 0, 0, 0);
        }
        // bias + relu + pack: D rows (j) = (reg&3)+8*(reg>>2)+4*hq, col (m) = lm
        #pragma unroll
        for(int q = 0; q < 4; ++q){
            float4 bs = *(const float4*)(b1 + j0 + w*32 + 8*q + 4*hq);
            float bsv[4] = {bs.x, bs.y, bs.z, bs.w};
            short4v p0, p1;
            #pragma unroll
            for(int r = 0; r < 4; ++r){
                float v0 = a0[4*q+r] + bsv[r]; v0 = v0 > 0.f ? v0 : 0.f;
                float v1 = a1[4*q+r] + bsv[r]; v1 = v1 > 0.f ? v1 : 0.f;
                p0[r] = f2bs(v0); p1[r] = f2bs(v1);
            }
            *(short4v*)((short*)sst + lm*136      + w*32 + 8*q + 4*hq) = p0;
            *(short4v*)((short*)sst + (32+lm)*136 + w*32 + 8*q + 4*hq) = p1;
        }
        __syncthreads();
        // ---- FF2: wave = (m-tile mt2, K-half kh); acc2 persists across j-tiles
        #pragma unroll
        for(int ks = 0; ks < 4; ++ks){
            int ksg = kh*4 + ks;
            short8 sf = *(const short8*)((const short*)sst + (mt2*32+lm)*136 + ksg*16 + hq*8);
            #pragma unroll
            for(int cct = 0; cct < 3; ++cct){
                short8 wf2 = *(const short8*)((const short*)w2t + (cct*32+lm)*136 + ksg*16 + hq*8);
                acc2[cct] = __builtin_amdgcn_mfma_f32_32x32x16_bf16(wf2, sf, acc2[cct], 0, 0, 0);
            }
        }
    }
    // ---- epilogue: reduce K-halves across wave pairs, add bias + residual
    __syncthreads();
    if(kh == 1){
        #pragma unroll
        for(int cct = 0; cct < 3; ++cct)
            #pragma unroll
            for(int q = 0; q < 4; ++q){
                float4 v;
                v.x = acc2[cct][4*q+0]; v.y = acc2[cct][4*q+1];
                v.z = acc2[cct][4*q+2]; v.w = acc2[cct][4*q+3];
                *(float4*)(red + mt2*3072 + cct*1024 + lane*16 + 4*q) = v;
            }
    }
    __syncthreads();
    if(kh == 0){
        int row = r0 + mt2*32 + lm;
        #pragma unroll
        for(int cct = 0; cct < 3; ++cct){
            #pragma unroll
            for(int q = 0; q < 4; ++q){
                int c = cct*32 + 8*q + 4*hq;
                float4 rv  = *(const float4*)(red + mt2*3072 + cct*1024 + lane*16 + 4*q);
                float4 b2v = *(const float4*)(b2 + c);
                float4 res = *(const float4*)(h1 + (size_t)row*96 + c);
                float4 o;
                o.x = acc2[cct][4*q+0] + rv.x + b2v.x + res.x;
                o.y = acc2[cct][4*q+1] + rv.y + b2v.y + res.y;
                o.z = acc2[cct][4*q+2] + rv.z + b2v.z + res.z;
                o.w = acc2[cct][4*q+3] + rv.w + b2v.w + res.w;
                *(float4*)(h2pre + (size_t)row*96 + c) = o;
            }
        }
    }
}

// ---------------- K6: LN2 -> LNf -> transpose -> fp32 out (unchanged) ----------------
__global__ void ln2f_kernel(const float* __restrict__ in, const float* __restrict__ g2,
                            const float* __restrict__ bt2, const float* __restrict__ gf,
                            const float* __restrict__ btf, float* __restrict__ out){
    __shared__ float zt[96*65];
    int wave = threadIdx.x/64, lane = threadIdx.x%64;
    int r0 = blockIdx.x*64;
    for(int rw = 0; rw < 16; ++rw){
        int tt = wave*16 + rw;
        size_t row = (size_t)r0 + tt;
        const float* p = in + row*96;
        float v0 = p[lane];
        float v1 = (lane < 32) ? p[64 + lane] : 0.f;
        float s = v0 + v1;
        for(int off = 32; off; off >>= 1) s += __shfl_down(s, off);
        s = __shfl(s, 0);
        float mu = s*(1.0f/96.0f);
        float d0 = v0 - mu, d1 = (lane < 32) ? (v1 - mu) : 0.f;
        float q = d0*d0 + d1*d1;
        for(int off = 32; off; off >>= 1) q += __shfl_down(q, off);
        q = __shfl(q, 0);
        float rstd = rsqrtf(q*(1.0f/96.0f) + 1e-5f);
        float y0 = d0*rstd*g2[lane] + bt2[lane];
        float y1 = (lane < 32) ? (d1*rstd*g2[64 + lane] + bt2[64 + lane]) : 0.f;
        s = y0 + y1;
        for(int off = 32; off; off >>= 1) s += __shfl_down(s, off);
        s = __shfl(s, 0);
        mu = s*(1.0f/96.0f);
        d0 = y0 - mu; d1 = (lane < 32) ? (y1 - mu) : 0.f;
        q = d0*d0 + d1*d1;
        for(int off = 32; off; off >>= 1) q += __shfl_down(q, off);
        q = __shfl(q, 0);
        rstd = rsqrtf(q*(1.0f/96.0f) + 1e-5f);
        zt[lane*65 + tt] = d0*rstd*gf[lane] + btf[lane];
        if(lane < 32)
            zt[(64 + lane)*65 + tt] = d1*rstd*gf[64 + lane] + btf[64 + lane];
    }
    __syncthreads();
    int b  = r0 / T;
    int t0 = r0 % T;
    for(int e = threadIdx.x; e < 96*64; e += 256){
        int c = e/64, tt = e%64;
        out[(size_t)b*C*T + (size_t)c*T + t0 + tt] = zt[c*65 + tt];
    }
}

extern "C" void kernel_launch(void* const* d_in, const int* in_sizes, int n_in,
                              void* d_out, int out_size, void* d_ws, size_t ws_size,
                              hipStream_t stream) {
    const float* x     = (const float*)d_in[0];
    const float* w_qkv = (const float*)d_in[1];
    const float* b_qkv = (const float*)d_in[2];
    const float* w_out = (const float*)d_in[3];
    const float* b_out = (const float*)d_in[4];
    const float* ln1_g = (const float*)d_in[5];
    const float* ln1_b = (const float*)d_in[6];
    const float* w_ff1 = (const float*)d_in[7];
    const float* b_ff1 = (const float*)d_in[8];
    const float* w_ff2 = (const float*)d_in[9];
    const float* b_ff2 = (const float*)d_in[10];
    const float* ln2_g = (const float*)d_in[11];
    const float* ln2_b = (const float*)d_in[12];
    const float* lnf_g = (const float*)d_in[13];
    const float* lnf_b = (const float*)d_in[14];
    float* out = (float*)d_out;

    // Workspace (peak BT*384 floats = 25.2 MB, same as round 2):
    //   [0, BT*288)        qkv (dead after attn) -> h1pre/h1/h2pre
    //   [BT*288, BT*384)   ctx (dead after outproj) -> w1b, w2b, h1b
    float* ws    = (float*)d_ws;
    float* qkv   = ws;
    float* ctx   = ws + (size_t)BT*288;
    float* h1pre = ws;
    float* h1    = ws + (size_t)BT*96;
    float* h2pre = ws + (size_t)BT*192;
    bf16*  w1b   = (bf16*)(ws + (size_t)BT*288);
    bf16*  w2b   = w1b + (size_t)FFD*C;
    bf16*  h1b   = w2b + (size_t)FFD*C;

    qkv_kernel    <<<BT/32, 256, 0, stream>>>(x, w_qkv, b_qkv, qkv);
    attn_kernel   <<<B*NH*(T/QT), 128, 0, stream>>>(qkv, ctx);
    outproj_kernel<<<BT/32, 256, 0, stream>>>(ctx, w_out, b_out, x, h1pre);
    cvtw_kernel   <<<(FFD*C + 255)/256, 256, 0, stream>>>(w_ff1, w_ff2, w1b, w2b);
    ln_kernel     <<<BT/4, 256, 0, stream>>>(h1pre, ln1_g, ln1_b, h1, h1b);
    ff_kernel     <<<BT/64, 256, 0, stream>>>(h1b, h1, w1b, b_ff1, w2b, b_ff2, h2pre);
    ln2f_kernel   <<<BT/64, 256, 0, stream>>>(h2pre, ln2_g, ln2_b, lnf_g, lnf_b, out);
}

// Round 4
// 248.496 us; speedup vs baseline: 3.4306x; 1.3978x over previous
//
#include <hip/hip_runtime.h>
#include <hip/hip_bf16.h>

#define B 8
#define T 2048
#define C 96
#define NH 3
#define HD 32
#define FFD 2048
#define HALF_W 32
#define BT (B*T)

typedef __hip_bfloat16 bf16;
typedef __attribute__((ext_vector_type(8))) short short8;
typedef __attribute__((ext_vector_type(4))) short short4v;
typedef __attribute__((ext_vector_type(16))) float floatx16;

__device__ __forceinline__ short f2bs(float v){
    __hip_bfloat16 h = __float2bfloat16(v);
    return *reinterpret_cast<short*>(&h);
}
__device__ __forceinline__ float bs2f(short s){
    unsigned u = ((unsigned)(unsigned short)s) << 16;
    return __uint_as_float(u);
}

// ---------------- K0: convert all weights to bf16 ----------------
// layout in weights region: wq[27648] | wout[9216] | w1[196608] | w2[196608]
__global__ void cvtw_kernel(const float* __restrict__ wq, const float* __restrict__ wo,
                            const float* __restrict__ w1, const float* __restrict__ w2,
                            bf16* __restrict__ dst){
    int i = blockIdx.x*256 + threadIdx.x;
    if(i < 27648)       dst[i] = __float2bfloat16(wq[i]);
    else if(i < 36864)  dst[i] = __float2bfloat16(wo[i-27648]);
    else if(i < 233472) dst[i] = __float2bfloat16(w1[i-36864]);
    else if(i < 430080) dst[i] = __float2bfloat16(w2[i-233472]);
}

// ---------------- K1: QKV projection, MFMA ----------------
// grid 256 (64 t-rows each), block 256. A=wq rows (o), B=x^T rows (t), D[o][t].
// Also emits xt (fp32 transposed x) for the outproj residual.
__global__ __launch_bounds__(256) void qkv_kernel(
    const float* __restrict__ x, const bf16* __restrict__ wq,
    const float* __restrict__ bias, bf16* __restrict__ qkvb, float* __restrict__ xt){
    __shared__ float xs[96*68];   // [c][t], stride 68 (16B-aligned, conflict-light)
    int b  = blockIdx.x >> 5;            // T/64 = 32 tiles per batch
    int t0 = (blockIdx.x & 31) * 64;
    for(int e = threadIdx.x; e < 96*16; e += 256){
        int c = e >> 4, t4 = e & 15;
        float4 v = *(const float4*)(x + (size_t)b*C*T + (size_t)c*T + t0 + t4*4);
        *(float4*)(xs + c*68 + t4*4) = v;
    }
    __syncthreads();
    // xt write (coalesced): thread e -> row t=e/96, col c=e%96
    int r0 = b*T + t0;
    for(int e = threadIdx.x; e < 96*64; e += 256){
        int t = e/96, c = e%96;
        xt[(size_t)(r0 + t)*96 + c] = xs[c*68 + t];
    }
    const int w = threadIdx.x >> 6, lane = threadIdx.x & 63;
    const int lm = lane & 31, hq = lane >> 5;
    // B-fragments for both m(=t)-tiles from LDS (conflict-free scalar reads)
    short8 bfr[2][6];
    #pragma unroll
    for(int mtl = 0; mtl < 2; ++mtl)
        #pragma unroll
        for(int ks = 0; ks < 6; ++ks){
            short8 v;
            #pragma unroll
            for(int i = 0; i < 8; ++i)
                v[i] = f2bs(xs[(ks*16 + hq*8 + i)*68 + mtl*32 + lm]);
            bfr[mtl][ks] = v;
        }
    // acc-tile list: wave w handles o-tiles {w, w+4} x mt {0,1}; waves 0/1 split tile 8
    int nacc = (w < 2) ? 5 : 4;
    int ots[5] = {w, w, w+4, w+4, 8};
    int mts[5] = {0, 1, 0,   1,   w};
    floatx16 acc[5];
    #pragma unroll
    for(int i = 0; i < 5; ++i)
        #pragma unroll
        for(int r = 0; r < 16; ++r) acc[i][r] = 0.f;
    #pragma unroll
    for(int i = 0; i < 5; ++i){
        if(i < nacc){
            #pragma unroll
            for(int ks = 0; ks < 6; ++ks){
                short8 af = *(const short8*)((const short*)wq
                              + (size_t)(ots[i]*32 + lm)*96 + ks*16 + hq*8);
                acc[i] = __builtin_amdgcn_mfma_f32_32x32x16_bf16(af, bfr[mts[i]][ks], acc[i], 0,0,0);
            }
        }
    }
    #pragma unroll
    for(int i = 0; i < 5; ++i){
        if(i < nacc){
            int row = r0 + mts[i]*32 + lm;
            int ob  = ots[i]*32;
            #pragma unroll
            for(int q = 0; q < 4; ++q){
                float4 bv = *(const float4*)(bias + ob + 8*q + 4*hq);
                short4v pk;
                pk[0] = f2bs(acc[i][4*q+0] + bv.x);
                pk[1] = f2bs(acc[i][4*q+1] + bv.y);
                pk[2] = f2bs(acc[i][4*q+2] + bv.z);
                pk[3] = f2bs(acc[i][4*q+3] + bv.w);
                *(short4v*)((short*)qkvb + (size_t)row*288 + ob + 8*q + 4*hq) = pk;
            }
        }
    }
}

// ---------------- K2: banded attention (single pass, shifted exp) ----------------
#define QT 128
#define KT (QT + 2*HALF_W)   // 192
__global__ __launch_bounds__(128) void attn_kernel(const bf16* __restrict__ qkvb,
                                                   bf16* __restrict__ ctxb){
    __shared__ float Ks[KT*33];
    __shared__ float Vs[KT*33];
    int blk = blockIdx.x;
    int ntile = T/QT;
    int b   = blk / (NH*ntile);
    int rem = blk % (NH*ntile);
    int h   = rem / ntile;
    int t0  = (rem % ntile) * QT;
    for(int e = threadIdx.x; e < KT*4; e += 128){   // short8 chunks
        int i = e >> 2, d8 = e & 3;
        int s = t0 - HALF_W + i;
        float kv[8], vv[8];
        if(s >= 0 && s < T){
            const short* row = (const short*)qkvb + (size_t)(b*T + s)*288 + h*HD + d8*8;
            short8 k8 = *(const short8*)(row + 96);
            short8 v8 = *(const short8*)(row + 192);
            #pragma unroll
            for(int j = 0; j < 8; ++j){ kv[j] = bs2f(k8[j]); vv[j] = bs2f(v8[j]); }
        } else {
            #pragma unroll
            for(int j = 0; j < 8; ++j){ kv[j] = 0.f; vv[j] = 0.f; }
        }
        #pragma unroll
        for(int j = 0; j < 8; ++j){
            Ks[i*33 + d8*8 + j] = kv[j];
            Vs[i*33 + d8*8 + j] = vv[j];
        }
    }
    __syncthreads();
    int t = t0 + threadIdx.x;
    float q[HD];
    {
        const short* qrow = (const short*)qkvb + (size_t)(b*T + t)*288 + h*HD;
        #pragma unroll
        for(int d8 = 0; d8 < 4; ++d8){
            short8 q8 = *(const short8*)(qrow + d8*8);
            #pragma unroll
            for(int j = 0; j < 8; ++j) q[d8*8+j] = bs2f(q8[j]);
        }
    }
    const float scale = 0.17677669529663687f;   // 1/sqrt(32)
    float l = 0.f;
    float o[HD];
    #pragma unroll
    for(int d = 0; d < HD; ++d) o[d] = 0.f;
    #pragma unroll 4
    for(int k = 0; k <= 2*HALF_W; ++k){
        int s = t - HALF_W + k;
        int li = threadIdx.x + k;
        float sc = 0.f;
        #pragma unroll
        for(int d = 0; d < HD; ++d) sc += q[d]*Ks[li*33 + d];
        // scores are O(1); shift by 20 instead of a max pass (exp range is huge)
        float p = __expf(sc*scale - 20.0f);
        if(s < 0 || s >= T) p = 0.f;
        l += p;
        #pragma unroll
        for(int d = 0; d < HD; ++d) o[d] += p*Vs[li*33 + d];
    }
    float inv = 1.0f/l;
    short* crow = (short*)ctxb + (size_t)(b*T + t)*96 + h*HD;
    #pragma unroll
    for(int d = 0; d < HD; ++d) crow[d] = f2bs(o[d]*inv);
}

// ---------------- K3: output projection + residual, MFMA, no LDS ----------------
// grid 256, block 256. A=w_out rows (c), B=ctx rows (m), D[c][m].
__global__ __launch_bounds__(256) void outproj_kernel(
    const bf16* __restrict__ ctxb, const bf16* __restrict__ wo,
    const float* __restrict__ bias, const float* __restrict__ xt,
    float* __restrict__ h1pre){
    const int w = threadIdx.x >> 6, lane = threadIdx.x & 63;
    const int lm = lane & 31, hq = lane >> 5;
    const int mt = w & 1, ch = w >> 1;
    const int r0 = blockIdx.x * 64;
    short8 bfr[6];
    #pragma unroll
    for(int ks = 0; ks < 6; ++ks)
        bfr[ks] = *(const short8*)((const short*)ctxb
                    + (size_t)(r0 + mt*32 + lm)*96 + ks*16 + hq*8);
    int nacc = ch ? 1 : 2;
    floatx16 acc[2];
    #pragma unroll
    for(int i = 0; i < 2; ++i)
        #pragma unroll
        for(int r = 0; r < 16; ++r) acc[i][r] = 0.f;
    #pragma unroll
    for(int i = 0; i < 2; ++i){
        if(i < nacc){
            int ct = ch ? 2 : i;
            #pragma unroll
            for(int ks = 0; ks < 6; ++ks){
                short8 af = *(const short8*)((const short*)wo
                              + (size_t)(ct*32 + lm)*96 + ks*16 + hq*8);
                acc[i] = __builtin_amdgcn_mfma_f32_32x32x16_bf16(af, bfr[ks], acc[i], 0,0,0);
            }
        }
    }
    int row = r0 + mt*32 + lm;
    #pragma unroll
    for(int i = 0; i < 2; ++i){
        if(i < nacc){
            int ct = ch ? 2 : i;
            #pragma unroll
            for(int q = 0; q < 4; ++q){
                int c = ct*32 + 8*q + 4*hq;
                float4 bv = *(const float4*)(bias + c);
                float4 xv = *(const float4*)(xt + (size_t)row*96 + c);
                float4 ov;
                ov.x = acc[i][4*q+0] + bv.x + xv.x;
                ov.y = acc[i][4*q+1] + bv.y + xv.y;
                ov.z = acc[i][4*q+2] + bv.z + xv.z;
                ov.w = acc[i][4*q+3] + bv.w + xv.w;
                *(float4*)(h1pre + (size_t)row*96 + c) = ov;
            }
        }
    }
}

// ---------------- K4: LayerNorm fp32->fp32 + bf16 copy (unchanged) ----------------
__global__ void ln_kernel(const float* __restrict__ in, const float* __restrict__ g,
                          const float* __restrict__ bb, float* __restrict__ out,
                          bf16* __restrict__ outb){
    int wave = threadIdx.x/64, lane = threadIdx.x%64;
    size_t row = (size_t)blockIdx.x*4 + wave;
    const float* p = in + row*96;
    float v0 = p[lane];
    float v1 = (lane < 32) ? p[64 + lane] : 0.f;
    float s = v0 + v1;
    for(int off = 32; off; off >>= 1) s += __shfl_down(s, off);
    s = __shfl(s, 0);
    float mu = s*(1.0f/96.0f);
    float d0 = v0 - mu, d1 = (lane < 32) ? (v1 - mu) : 0.f;
    float q = d0*d0 + d1*d1;
    for(int off = 32; off; off >>= 1) q += __shfl_down(q, off);
    q = __shfl(q, 0);
    float rstd = rsqrtf(q*(1.0f/96.0f) + 1e-5f);
    float* po = out + row*96;
    bf16* pb = outb + row*96;
    float y0 = d0*rstd*g[lane] + bb[lane];
    po[lane] = y0;
    pb[lane] = __float2bfloat16(y0);
    if(lane < 32){
        float y1 = d1*rstd*g[64 + lane] + bb[64 + lane];
        po[64 + lane] = y1;
        pb[64 + lane] = __float2bfloat16(y1);
    }
}

// ---------------- K5a: FF1 = relu(h1@w1^T+b1) -> blocked bf16, barrier-free ----------------
// grid (RPP/64)*16, block 256. A=w1 rows (j), B=h rows (m). D[j][m].
// s_blk layout: [ks 0..127][mb 0..MBT)[hq 2][lm 32][8 shorts]  (== B-fragment order)
__global__ __launch_bounds__(256) void ff1_kernel(
    const bf16* __restrict__ h1b, const bf16* __restrict__ w1b,
    const float* __restrict__ b1, bf16* __restrict__ sblk,
    int row_off, int nmb, int MBT){
    const int jblk = blockIdx.x / nmb;
    const int mblk = blockIdx.x % nmb;
    const int w = threadIdx.x >> 6, lane = threadIdx.x & 63;
    const int lm = lane & 31, hq = lane >> 5;
    const int mt = w & 1, jh = w >> 1;
    const int r0 = row_off + mblk*64;
    const int j0 = jblk*128;
    const int mb = mblk*2 + mt;
    short8 hf[6];
    #pragma unroll
    for(int ks = 0; ks < 6; ++ks)
        hf[ks] = *(const short8*)((const short*)h1b
                   + (size_t)(r0 + mt*32 + lm)*96 + ks*16 + hq*8);
    floatx16 acc[2];
    #pragma unroll
    for(int i = 0; i < 2; ++i)
        #pragma unroll
        for(int r = 0; r < 16; ++r) acc[i][r] = 0.f;
    #pragma unroll
    for(int jt2 = 0; jt2 < 2; ++jt2){
        int jt = j0 + (jh*2 + jt2)*32;
        #pragma unroll
        for(int ks = 0; ks < 6; ++ks){
            short8 af = *(const short8*)((const short*)w1b
                          + (size_t)(jt + lm)*96 + ks*16 + hq*8);
            acc[jt2] = __builtin_amdgcn_mfma_f32_32x32x16_bf16(af, hf[ks], acc[jt2], 0,0,0);
        }
    }
    #pragma unroll
    for(int jt2 = 0; jt2 < 2; ++jt2){
        int jt = j0 + (jh*2 + jt2)*32;    // multiple of 32
        #pragma unroll
        for(int q = 0; q < 4; ++q){
            float4 bv = *(const float4*)(b1 + jt + 8*q + 4*hq);
            float vr[4] = {acc[jt2][4*q+0] + bv.x, acc[jt2][4*q+1] + bv.y,
                           acc[jt2][4*q+2] + bv.z, acc[jt2][4*q+3] + bv.w};
            short4v pk;
            #pragma unroll
            for(int r = 0; r < 4; ++r) pk[r] = f2bs(vr[r] > 0.f ? vr[r] : 0.f);
            int ks = (jt >> 4) + (q >> 1);
            size_t off = ((((size_t)ks*MBT + mb)*2 + (q & 1))*32 + lm)*8 + 4*hq;
            *(short4v*)((short*)sblk + off) = pk;
        }
    }
}

// ---------------- K5b: FF2 = s@w2^T + b2 + h1, barrier-free k-loop ----------------
// grid RPP/64, block 256, waves=(mt,kh). s from blocked global (coalesced), w2 L2-hot.
__global__ __launch_bounds__(256) void ff2_kernel(
    const bf16* __restrict__ sblk, const bf16* __restrict__ w2b,
    const float* __restrict__ b2, const float* __restrict__ h1,
    float* __restrict__ h2pre, int row_off, int MBT){
    __shared__ float red[6144];
    const int w = threadIdx.x >> 6, lane = threadIdx.x & 63;
    const int lm = lane & 31, hq = lane >> 5;
    const int mt2 = w & 1, kh = w >> 1;
    const int r0 = row_off + blockIdx.x*64;
    const int mb = blockIdx.x*2 + mt2;
    floatx16 acc2[3];
    #pragma unroll
    for(int i = 0; i < 3; ++i)
        #pragma unroll
        for(int r = 0; r < 16; ++r) acc2[i][r] = 0.f;
    #pragma unroll 2
    for(int ks = kh*64; ks < kh*64 + 64; ++ks){
        short8 sf = *(const short8*)((const short*)sblk
                      + ((((size_t)ks*MBT + mb)*2 + hq)*32 + lm)*8);
        #pragma unroll
        for(int ct = 0; ct < 3; ++ct){
            short8 wf = *(const short8*)((const short*)w2b
                          + (size_t)(ct*32 + lm)*FFD + ks*16 + hq*8);
            acc2[ct] = __builtin_amdgcn_mfma_f32_32x32x16_bf16(wf, sf, acc2[ct], 0,0,0);
        }
    }
    __syncthreads();
    if(kh == 1){
        #pragma unroll
        for(int cct = 0; cct < 3; ++cct)
            #pragma unroll
            for(int q = 0; q < 4; ++q){
                float4 v;
                v.x = acc2[cct][4*q+0]; v.y = acc2[cct][4*q+1];
                v.z = acc2[cct][4*q+2]; v.w = acc2[cct][4*q+3];
                *(float4*)(red + mt2*3072 + cct*1024 + lane*16 + 4*q) = v;
            }
    }
    __syncthreads();
    if(kh == 0){
        int row = r0 + mt2*32 + lm;
        #pragma unroll
        for(int cct = 0; cct < 3; ++cct){
            #pragma unroll
            for(int q = 0; q < 4; ++q){
                int c = cct*32 + 8*q + 4*hq;
                float4 rv  = *(const float4*)(red + mt2*3072 + cct*1024 + lane*16 + 4*q);
                float4 b2v = *(const float4*)(b2 + c);
                float4 res = *(const float4*)(h1 + (size_t)row*96 + c);
                float4 o;
                o.x = acc2[cct][4*q+0] + rv.x + b2v.x + res.x;
                o.y = acc2[cct][4*q+1] + rv.y + b2v.y + res.y;
                o.z = acc2[cct][4*q+2] + rv.z + b2v.z + res.z;
                o.w = acc2[cct][4*q+3] + rv.w + b2v.w + res.w;
                *(float4*)(h2pre + (size_t)row*96 + c) = o;
            }
        }
    }
}

// ---------------- K5-fallback: round-3 fused FF (only if ws too small) ----------------
__global__ __launch_bounds__(256) void ff_fused_kernel(
    const bf16* __restrict__ h1b, const float* __restrict__ h1,
    const bf16* __restrict__ w1b, const float* __restrict__ b1,
    const bf16* __restrict__ w2b, const float* __restrict__ b2,
    float* __restrict__ h2pre){
    __shared__ __align__(16) char smem[26624 + 26112 + 17408];
    bf16* w1t = (bf16*)smem;
    bf16* w2t = (bf16*)(smem + 26624);
    bf16* sst = (bf16*)(smem + 26624 + 26112);
    float* red = (float*)smem;
    const int tid = threadIdx.x;
    const int w = tid >> 6, lane = tid & 63;
    const int lm = lane & 31, hq = lane >> 5;
    const int r0 = blockIdx.x * 64;
    const int mt2 = w & 1, kh = w >> 1;
    short8 hf[2][6];
    #pragma unroll
    for(int mt = 0; mt < 2; ++mt)
        #pragma unroll
        for(int ks = 0; ks < 6; ++ks)
            hf[mt][ks] = *(const short8*)((const short*)h1b
                          + (size_t)(r0 + mt*32 + lm)*96 + ks*16 + hq*8);
    floatx16 acc2[3];
    #pragma unroll
    for(int i = 0; i < 3; ++i)
        #pragma unroll
        for(int r = 0; r < 16; ++r) acc2[i][r] = 0.f;
    for(int jt = 0; jt < 16; ++jt){
        const int j0 = jt * 128;
        __syncthreads();
        #pragma unroll
        for(int i = 0; i < 6; ++i){
            int e = tid + i*256;
            int row = e/12, c8 = e%12;
            uint4 v = *(const uint4*)((const short*)w1b + (size_t)(j0+row)*96 + c8*8);
            *(uint4*)((short*)w1t + row*104 + c8*8) = v;
        }
        #pragma unroll
        for(int i = 0; i < 6; ++i){
            int e = tid + i*256;
            int row = e/16, j8 = e%16;
            uint4 v = *(const uint4*)((const short*)w2b + (size_t)row*FFD + j0 + j8*8);
            *(uint4*)((short*)w2t + row*136 + j8*8) = v;
        }
        __syncthreads();
        floatx16 a0, a1;
        #pragma unroll
        for(int r = 0; r < 16; ++r){ a0[r] = 0.f; a1[r] = 0.f; }
        #pragma unroll
        for(int ks = 0; ks < 6; ++ks){
            short8 wf = *(const short8*)((const short*)w1t + (w*32+lm)*104 + ks*16 + hq*8);
            a0 = __builtin_amdgcn_mfma_f32_32x32x16_bf16(wf, hf[0][ks], a0, 0, 0, 0);
            a1 = __builtin_amdgcn_mfma_f32_32x32x16_bf16(wf, hf[1][ks], a1, 0, 0, 0);
        }
        #pragma unroll
        for(int q = 0; q < 4; ++q){
            float4 bs = *(const float4*)(b1 + j0 + w*32 + 8*q + 4*hq);
            float bsv[4] = {bs.x, bs.y, bs.z, bs.w};
            short4v p0, p1;
            #pragma unroll
            for(int r = 0; r < 4; ++r){
                float v0 = a0[4*q+r] + bsv[r]; v0 = v0 > 0.f ? v0 : 0.f;
                float v1 = a1[4*q+r] + bsv[r]; v1 = v1 > 0.f ? v1 : 0.f;
                p0[r] = f2bs(v0); p1[r] = f2bs(v1);
            }
            *(short4v*)((short*)sst + lm*136      + w*32 + 8*q + 4*hq) = p0;
            *(short4v*)((short*)sst + (32+lm)*136 + w*32 + 8*q + 4*hq) = p1;
        }
        __syncthreads();
        #pragma unroll
        for(int ks = 0; ks < 4; ++ks){
            int ksg = kh*4 + ks;
            short8 sf = *(const short8*)((const short*)sst + (mt2*32+lm)*136 + ksg*16 + hq*8);
            #pragma unroll
            for(int cct = 0; cct < 3; ++cct){
                short8 wf2 = *(const short8*)((const short*)w2t + (cct*32+lm)*136 + ksg*16 + hq*8);
                acc2[cct] = __builtin_amdgcn_mfma_f32_32x32x16_bf16(wf2, sf, acc2[cct], 0, 0, 0);
            }
        }
    }
    __syncthreads();
    if(kh == 1){
        #pragma unroll
        for(int cct = 0; cct < 3; ++cct)
            #pragma unroll
            for(int q = 0; q < 4; ++q){
                float4 v;
                v.x = acc2[cct][4*q+0]; v.y = acc2[cct][4*q+1];
                v.z = acc2[cct][4*q+2]; v.w = acc2[cct][4*q+3];
                *(float4*)(red + mt2*3072 + cct*1024 + lane*16 + 4*q) = v;
            }
    }
    __syncthreads();
    if(kh == 0){
        int row = r0 + mt2*32 + lm;
        #pragma unroll
        for(int cct = 0; cct < 3; ++cct){
            #pragma unroll
            for(int q = 0; q < 4; ++q){
                int c = cct*32 + 8*q + 4*hq;
                float4 rv  = *(const float4*)(red + mt2*3072 + cct*1024 + lane*16 + 4*q);
                float4 b2v = *(const float4*)(b2 + c);
                float4 res = *(const float4*)(h1 + (size_t)row*96 + c);
                float4 o;
                o.x = acc2[cct][4*q+0] + rv.x + b2v.x + res.x;
                o.y = acc2[cct][4*q+1] + rv.y + b2v.y + res.y;
                o.z = acc2[cct][4*q+2] + rv.z + b2v.z + res.z;
                o.w = acc2[cct][4*q+3] + rv.w + b2v.w + res.w;
                *(float4*)(h2pre + (size_t)row*96 + c) = o;
            }
        }
    }
}

// ---------------- K6: LN2 -> LNf -> transpose -> fp32 out (unchanged) ----------------
__global__ void ln2f_kernel(const float* __restrict__ in, const float* __restrict__ g2,
                            const float* __restrict__ bt2, const float* __restrict__ gf,
                            const float* __restrict__ btf, float* __restrict__ out){
    __shared__ float zt[96*65];
    int wave = threadIdx.x/64, lane = threadIdx.x%64;
    int r0 = blockIdx.x*64;
    for(int rw = 0; rw < 16; ++rw){
        int tt = wave*16 + rw;
        size_t row = (size_t)r0 + tt;
        const float* p = in + row*96;
        float v0 = p[lane];
        float v1 = (lane < 32) ? p[64 + lane] : 0.f;
        float s = v0 + v1;
        for(int off = 32; off; off >>= 1) s += __shfl_down(s, off);
        s = __shfl(s, 0);
        float mu = s*(1.0f/96.0f);
        float d0 = v0 - mu, d1 = (lane < 32) ? (v1 - mu) : 0.f;
        float q = d0*d0 + d1*d1;
        for(int off = 32; off; off >>= 1) q += __shfl_down(q, off);
        q = __shfl(q, 0);
        float rstd = rsqrtf(q*(1.0f/96.0f) + 1e-5f);
        float y0 = d0*rstd*g2[lane] + bt2[lane];
        float y1 = (lane < 32) ? (d1*rstd*g2[64 + lane] + bt2[64 + lane]) : 0.f;
        s = y0 + y1;
        for(int off = 32; off; off >>= 1) s += __shfl_down(s, off);
        s = __shfl(s, 0);
        mu = s*(1.0f/96.0f);
        d0 = y0 - mu; d1 = (lane < 32) ? (y1 - mu) : 0.f;
        q = d0*d0 + d1*d1;
        for(int off = 32; off; off >>= 1) q += __shfl_down(q, off);
        q = __shfl(q, 0);
        rstd = rsqrtf(q*(1.0f/96.0f) + 1e-5f);
        zt[lane*65 + tt] = d0*rstd*gf[lane] + btf[lane];
        if(lane < 32)
            zt[(64 + lane)*65 + tt] = d1*rstd*gf[64 + lane] + btf[64 + lane];
    }
    __syncthreads();
    int b  = r0 / T;
    int t0 = r0 % T;
    for(int e = threadIdx.x; e < 96*64; e += 256){
        int c = e/64, tt = e%64;
        out[(size_t)b*C*T + (size_t)c*T + t0 + tt] = zt[c*65 + tt];
    }
}

extern "C" void kernel_launch(void* const* d_in, const int* in_sizes, int n_in,
                              void* d_out, int out_size, void* d_ws, size_t ws_size,
                              hipStream_t stream) {
    const float* x     = (const float*)d_in[0];
    const float* w_qkv = (const float*)d_in[1];
    const float* b_qkv = (const float*)d_in[2];
    const float* w_out = (const float*)d_in[3];
    const float* b_out = (const float*)d_in[4];
    const float* ln1_g = (const float*)d_in[5];
    const float* ln1_b = (const float*)d_in[6];
    const float* w_ff1 = (const float*)d_in[7];
    const float* b_ff1 = (const float*)d_in[8];
    const float* w_ff2 = (const float*)d_in[9];
    const float* b_ff2 = (const float*)d_in[10];
    const float* ln2_g = (const float*)d_in[11];
    const float* ln2_b = (const float*)d_in[12];
    const float* lnf_g = (const float*)d_in[13];
    const float* lnf_b = (const float*)d_in[14];
    float* out = (float*)d_out;

    // ws map (bytes). Lifetime-overlapped; base footprint 23.7 MB:
    //   qkvb  [0, 9.44M)          dead after attn
    //   xt    [9.44M, 15.73M)     dead after outproj
    //   ctxb  [15.73M, 18.87M)    dead after outproj
    //   h1pre [0, 6.29M)          over dead qkvb
    //   h1    [6.29M, 12.58M)
    //   h1b   [12.58M, 15.73M)
    //   h2pre [15.73M, 22.02M)    over dead ctxb
    //   wts   [22.02M, 22.88M)
    //   s_blk [22.88M, +64MB/passes)
    char* wsb = (char*)d_ws;
    bf16*  qkvb  = (bf16*)wsb;
    float* xt    = (float*)(wsb + 9437184);
    bf16*  ctxb  = (bf16*)(wsb + 15728640);
    float* h1pre = (float*)wsb;
    float* h1    = (float*)(wsb + 6291456);
    bf16*  h1b   = (bf16*)(wsb + 12582912);
    float* h2pre = (float*)(wsb + 15728640);
    bf16*  wts   = (bf16*)(wsb + 22020096);
    bf16*  wqkvb = wts;
    bf16*  woutb = wts + 27648;
    bf16*  w1b   = wts + 36864;
    bf16*  w2b   = wts + 233472;
    bf16*  sblk  = (bf16*)(wsb + 22880256);

    const size_t base = 22880256;
    int passes = 0;                              // 0 => fused fallback
    if     (ws_size >= base + (size_t)67108864) passes = 1;
    else if(ws_size >= base + (size_t)33554432) passes = 2;
    else if(ws_size >= base + (size_t)16777216) passes = 4;
    else if(ws_size >= base + (size_t) 8388608) passes = 8;

    cvtw_kernel   <<<1680, 256, 0, stream>>>(w_qkv, w_out, w_ff1, w_ff2, wts);
    qkv_kernel    <<<BT/64, 256, 0, stream>>>(x, wqkvb, b_qkv, qkvb, xt);
    attn_kernel   <<<B*NH*(T/QT), 128, 0, stream>>>(qkvb, ctxb);
    outproj_kernel<<<BT/64, 256, 0, stream>>>(ctxb, woutb, b_out, xt, h1pre);
    ln_kernel     <<<BT/4, 256, 0, stream>>>(h1pre, ln1_g, ln1_b, h1, h1b);
    if(passes > 0){
        int RPP = BT / passes;
        int nmb = RPP / 64;
        int MBT = RPP / 32;
        for(int p = 0; p < passes; ++p){
            int row_off = p * RPP;
            ff1_kernel<<<nmb*16, 256, 0, stream>>>(h1b, w1b, b_ff1, sblk, row_off, nmb, MBT);
            ff2_kernel<<<nmb, 256, 0, stream>>>(sblk, w2b, b_ff2, h1, h2pre, row_off, MBT);
        }
    } else {
        ff_fused_kernel<<<BT/64, 256, 0, stream>>>(h1b, h1, w1b, b_ff1, w2b, b_ff2, h2pre);
    }
    ln2f_kernel   <<<BT/64, 256, 0, stream>>>(h2pre, ln2_g, ln2_b, lnf_g, lnf_b, out);
}

// Round 5
// 206.004 us; speedup vs baseline: 4.1382x; 1.2063x over previous
//
#include <hip/hip_runtime.h>
#include <hip/hip_bf16.h>

#define B 8
#define T 2048
#define C 96
#define NH 3
#define HD 32
#define FFD 2048
#define HALF_W 32
#define BT (B*T)

typedef __hip_bfloat16 bf16;
typedef __attribute__((ext_vector_type(8))) short short8;
typedef __attribute__((ext_vector_type(4))) short short4v;
typedef __attribute__((ext_vector_type(16))) float floatx16;

__device__ __forceinline__ short f2bs(float v){
    __hip_bfloat16 h = __float2bfloat16(v);
    return *reinterpret_cast<short*>(&h);
}
__device__ __forceinline__ float bs2f(short s){
    unsigned u = ((unsigned)(unsigned short)s) << 16;
    return __uint_as_float(u);
}
__device__ __forceinline__ int imin(int a, int b){ return a < b ? a : b; }
__device__ __forceinline__ int imax(int a, int b){ return a > b ? a : b; }

// ---------------- K0: convert all weights to bf16 ----------------
__global__ void cvtw_kernel(const float* __restrict__ wq, const float* __restrict__ wo,
                            const float* __restrict__ w1, const float* __restrict__ w2,
                            bf16* __restrict__ dst){
    int i = blockIdx.x*256 + threadIdx.x;
    if(i < 27648)       dst[i] = __float2bfloat16(wq[i]);
    else if(i < 36864)  dst[i] = __float2bfloat16(wo[i-27648]);
    else if(i < 233472) dst[i] = __float2bfloat16(w1[i-36864]);
    else if(i < 430080) dst[i] = __float2bfloat16(w2[i-233472]);
}

// ---------------- K1: QKV projection, MFMA, 32 rows/block ----------------
__global__ __launch_bounds__(256) void qkv_kernel(
    const float* __restrict__ x, const bf16* __restrict__ wq,
    const float* __restrict__ bias, bf16* __restrict__ qkvb, float* __restrict__ xt){
    __shared__ float xs[96*36];   // [c][t], stride 36
    int b  = blockIdx.x >> 6;            // T/32 = 64 tiles per batch
    int t0 = (blockIdx.x & 63) * 32;
    for(int e = threadIdx.x; e < 96*8; e += 256){
        int c = e >> 3, t4 = e & 7;
        *(float4*)(xs + c*36 + t4*4) =
            *(const float4*)(x + (size_t)b*C*T + (size_t)c*T + t0 + t4*4);
    }
    __syncthreads();
    int r0 = b*T + t0;
    for(int e = threadIdx.x; e < 768; e += 256){
        int t = e/24, c4 = e%24;
        float4 v;
        v.x = xs[(c4*4+0)*36 + t]; v.y = xs[(c4*4+1)*36 + t];
        v.z = xs[(c4*4+2)*36 + t]; v.w = xs[(c4*4+3)*36 + t];
        *(float4*)(xt + (size_t)(r0 + t)*96 + c4*4) = v;
    }
    const int w = threadIdx.x >> 6, lane = threadIdx.x & 63;
    const int lm = lane & 31, hq = lane >> 5;
    short8 bfr[6];
    #pragma unroll
    for(int ks = 0; ks < 6; ++ks){
        short8 v;
        #pragma unroll
        for(int i = 0; i < 8; ++i)
            v[i] = f2bs(xs[(ks*16 + hq*8 + i)*36 + lm]);
        bfr[ks] = v;
    }
    int nacc = (w == 0) ? 3 : 2;
    int ots[3] = {w, w+4, 8};
    floatx16 acc[3];
    #pragma unroll
    for(int i = 0; i < 3; ++i)
        #pragma unroll
        for(int r = 0; r < 16; ++r) acc[i][r] = 0.f;
    #pragma unroll
    for(int i = 0; i < 3; ++i){
        if(i < nacc){
            #pragma unroll
            for(int ks = 0; ks < 6; ++ks){
                short8 af = *(const short8*)((const short*)wq
                              + (size_t)(ots[i]*32 + lm)*96 + ks*16 + hq*8);
                acc[i] = __builtin_amdgcn_mfma_f32_32x32x16_bf16(af, bfr[ks], acc[i], 0,0,0);
            }
        }
    }
    #pragma unroll
    for(int i = 0; i < 3; ++i){
        if(i < nacc){
            int row = r0 + lm;
            int ob  = ots[i]*32;
            #pragma unroll
            for(int q = 0; q < 4; ++q){
                float4 bv = *(const float4*)(bias + ob + 8*q + 4*hq);
                short4v pk;
                pk[0] = f2bs(acc[i][4*q+0] + bv.x);
                pk[1] = f2bs(acc[i][4*q+1] + bv.y);
                pk[2] = f2bs(acc[i][4*q+2] + bv.z);
                pk[3] = f2bs(acc[i][4*q+3] + bv.w);
                *(short4v*)((short*)qkvb + (size_t)row*288 + ob + 8*q + 4*hq) = pk;
            }
        }
    }
}

// ---------------- K2: banded attention via MFMA ----------------
// grid B*NH*(T/128), block 256 (4 waves). Wave w: queries [t0+32w, t0+32w+32).
// S = K·Q^T (D[key][query]), masked exp (no max pass), P->LDS->A-frag, O = P·V^T.
__global__ __launch_bounds__(256) void attn_kernel(const bf16* __restrict__ qkvb,
                                                   bf16* __restrict__ ctxb){
    __shared__ __align__(16) short VtS[32*216];        // V^T [d][key0..191], stride 216
    __shared__ __align__(16) short PtS[4][32*104];     // per wave: P [query][key0..95]
    __shared__ float LsS[4][32];
    int blk = blockIdx.x;
    int ntile = T/128;
    int b   = blk / (NH*ntile);
    int rem = blk % (NH*ntile);
    int h   = rem / ntile;
    int t0  = (rem % ntile) * 128;
    const int tid = threadIdx.x;
    const int w = tid >> 6, lane = tid & 63;
    const int lm = lane & 31, hq = lane >> 5;

    // stage V^T: keys kb in [0,192) <-> s = t0-32+kb (clamped; mask kills OOB)
    for(int e = tid; e < 384; e += 256){
        int kp = e >> 2, d8 = e & 3;          // keys 2kp,2kp+1; dims d8*8..+8
        int sa = imin(imax(t0 - 32 + 2*kp, 0), T-1);
        int sb = imin(imax(t0 - 32 + 2*kp + 1, 0), T-1);
        short8 va = *(const short8*)((const short*)qkvb + (size_t)(b*T+sa)*288 + 192 + h*32 + d8*8);
        short8 vb = *(const short8*)((const short*)qkvb + (size_t)(b*T+sb)*288 + 192 + h*32 + d8*8);
        #pragma unroll
        for(int j = 0; j < 8; ++j){
            int d = d8*8 + j;
            int val = (int)(unsigned short)va[j] | ((int)(unsigned short)vb[j] << 16);
            *(int*)(VtS + d*216 + 2*kp) = val;
        }
    }
    // ---- S phase: queries (B-frag), keys (A-frag), direct from global
    short8 qf0, qf1;
    {
        const short* qrow = (const short*)qkvb + (size_t)(b*T + t0 + 32*w + lm)*288 + h*32;
        qf0 = *(const short8*)(qrow + hq*8);
        qf1 = *(const short8*)(qrow + 16 + hq*8);
    }
    floatx16 S[3];
    #pragma unroll
    for(int sub = 0; sub < 3; ++sub){
        int srow = imin(imax(t0 + 32*w - 32 + sub*32 + lm, 0), T-1);
        const short* krow = (const short*)qkvb + (size_t)(b*T + srow)*288 + 96 + h*32;
        short8 kf0 = *(const short8*)(krow + hq*8);
        short8 kf1 = *(const short8*)(krow + 16 + hq*8);
        floatx16 z;
        #pragma unroll
        for(int r = 0; r < 16; ++r) z[r] = 0.f;
        z = __builtin_amdgcn_mfma_f32_32x32x16_bf16(kf0, qf0, z, 0,0,0);
        z = __builtin_amdgcn_mfma_f32_32x32x16_bf16(kf1, qf1, z, 0,0,0);
        S[sub] = z;
    }
    // ---- masked exp + row (query) sums. D layout: col=query=lm, reg->key.
    const float scale = 0.17677669529663687f;
    float part = 0.f;
    #pragma unroll
    for(int sub = 0; sub < 3; ++sub){
        #pragma unroll
        for(int r = 0; r < 16; ++r){
            int key_local = sub*32 + (r&3) + 8*(r>>2) + 4*hq;
            int s_glob = t0 + 32*w - 32 + key_local;
            int rel = key_local - lm;
            bool ok = (rel >= 0) && (rel <= 64) && (s_glob >= 0) && (s_glob < T);
            float p = ok ? __expf(S[sub][r]*scale) : 0.f;
            S[sub][r] = p;
            part += p;
        }
    }
    float ltot = part + __shfl_xor(part, 32);
    if(hq == 0) LsS[w][lm] = ltot;
    // ---- write P to LDS transposed: Pt[query=lm][key_local], bf16 pairs
    #pragma unroll
    for(int sub = 0; sub < 3; ++sub){
        #pragma unroll
        for(int q4 = 0; q4 < 4; ++q4){
            int kbase = sub*32 + 8*q4 + 4*hq;
            short4v pk;
            pk[0] = f2bs(S[sub][4*q4+0]);
            pk[1] = f2bs(S[sub][4*q4+1]);
            pk[2] = f2bs(S[sub][4*q4+2]);
            pk[3] = f2bs(S[sub][4*q4+3]);
            *(short4v*)(PtS[w] + lm*104 + kbase) = pk;
        }
    }
    __syncthreads();   // VtS ready (PtS/LsS are same-wave)
    // ---- PV: O[query][d] = sum_key P[q][k] * V[k][d]; A=Pt rows, B=Vt rows
    floatx16 O;
    #pragma unroll
    for(int r = 0; r < 16; ++r) O[r] = 0.f;
    #pragma unroll
    for(int ks = 0; ks < 6; ++ks){
        short8 pa = *(const short8*)(PtS[w] + lm*104 + ks*16 + hq*8);
        short8 vb = *(const short8*)(VtS + lm*216 + 32*w + ks*16 + hq*8);
        O = __builtin_amdgcn_mfma_f32_32x32x16_bf16(pa, vb, O, 0,0,0);
    }
    // ---- epilogue: divide by l, write ctx. D: reg->query row, col=lm=d.
    #pragma unroll
    for(int r = 0; r < 16; ++r){
        int qr = (r&3) + 8*(r>>2) + 4*hq;
        float linv = 1.f / LsS[w][qr];
        ((short*)ctxb)[(size_t)(b*T + t0 + 32*w + qr)*96 + h*32 + lm] = f2bs(O[r]*linv);
    }
}

// ---------------- K3: output projection + residual, MFMA, no LDS ----------------
__global__ __launch_bounds__(256) void outproj_kernel(
    const bf16* __restrict__ ctxb, const bf16* __restrict__ wo,
    const float* __restrict__ bias, const float* __restrict__ xt,
    float* __restrict__ h1pre){
    const int w = threadIdx.x >> 6, lane = threadIdx.x & 63;
    const int lm = lane & 31, hq = lane >> 5;
    const int mt = w & 1, ch = w >> 1;
    const int r0 = blockIdx.x * 64;
    short8 bfr[6];
    #pragma unroll
    for(int ks = 0; ks < 6; ++ks)
        bfr[ks] = *(const short8*)((const short*)ctxb
                    + (size_t)(r0 + mt*32 + lm)*96 + ks*16 + hq*8);
    int nacc = ch ? 1 : 2;
    floatx16 acc[2];
    #pragma unroll
    for(int i = 0; i < 2; ++i)
        #pragma unroll
        for(int r = 0; r < 16; ++r) acc[i][r] = 0.f;
    #pragma unroll
    for(int i = 0; i < 2; ++i){
        if(i < nacc){
            int ct = ch ? 2 : i;
            #pragma unroll
            for(int ks = 0; ks < 6; ++ks){
                short8 af = *(const short8*)((const short*)wo
                              + (size_t)(ct*32 + lm)*96 + ks*16 + hq*8);
                acc[i] = __builtin_amdgcn_mfma_f32_32x32x16_bf16(af, bfr[ks], acc[i], 0,0,0);
            }
        }
    }
    int row = r0 + mt*32 + lm;
    #pragma unroll
    for(int i = 0; i < 2; ++i){
        if(i < nacc){
            int ct = ch ? 2 : i;
            #pragma unroll
            for(int q = 0; q < 4; ++q){
                int c = ct*32 + 8*q + 4*hq;
                float4 bv = *(const float4*)(bias + c);
                float4 xv = *(const float4*)(xt + (size_t)row*96 + c);
                float4 ov;
                ov.x = acc[i][4*q+0] + bv.x + xv.x;
                ov.y = acc[i][4*q+1] + bv.y + xv.y;
                ov.z = acc[i][4*q+2] + bv.z + xv.z;
                ov.w = acc[i][4*q+3] + bv.w + xv.w;
                *(float4*)(h1pre + (size_t)row*96 + c) = ov;
            }
        }
    }
}

// ---------------- K4: LayerNorm fp32->fp32 + bf16 copy ----------------
__global__ void ln_kernel(const float* __restrict__ in, const float* __restrict__ g,
                          const float* __restrict__ bb, float* __restrict__ out,
                          bf16* __restrict__ outb){
    int wave = threadIdx.x/64, lane = threadIdx.x%64;
    size_t row = (size_t)blockIdx.x*4 + wave;
    const float* p = in + row*96;
    float v0 = p[lane];
    float v1 = (lane < 32) ? p[64 + lane] : 0.f;
    float s = v0 + v1;
    for(int off = 32; off; off >>= 1) s += __shfl_down(s, off);
    s = __shfl(s, 0);
    float mu = s*(1.0f/96.0f);
    float d0 = v0 - mu, d1 = (lane < 32) ? (v1 - mu) : 0.f;
    float q = d0*d0 + d1*d1;
    for(int off = 32; off; off >>= 1) q += __shfl_down(q, off);
    q = __shfl(q, 0);
    float rstd = rsqrtf(q*(1.0f/96.0f) + 1e-5f);
    float* po = out + row*96;
    bf16* pb = outb + row*96;
    float y0 = d0*rstd*g[lane] + bb[lane];
    po[lane] = y0;
    pb[lane] = __float2bfloat16(y0);
    if(lane < 32){
        float y1 = d1*rstd*g[64 + lane] + bb[64 + lane];
        po[64 + lane] = y1;
        pb[64 + lane] = __float2bfloat16(y1);
    }
}

// ---------------- K5a: FF1 -> blocked bf16 s, barrier-free ----------------
__global__ __launch_bounds__(256) void ff1_kernel(
    const bf16* __restrict__ h1b, const bf16* __restrict__ w1b,
    const float* __restrict__ b1, bf16* __restrict__ sblk,
    int row_off, int nmb, int MBT){
    const int jblk = blockIdx.x / nmb;
    const int mblk = blockIdx.x % nmb;
    const int w = threadIdx.x >> 6, lane = threadIdx.x & 63;
    const int lm = lane & 31, hq = lane >> 5;
    const int mt = w & 1, jh = w >> 1;
    const int r0 = row_off + mblk*64;
    const int j0 = jblk*128;
    const int mb = mblk*2 + mt;
    short8 hf[6];
    #pragma unroll
    for(int ks = 0; ks < 6; ++ks)
        hf[ks] = *(const short8*)((const short*)h1b
                   + (size_t)(r0 + mt*32 + lm)*96 + ks*16 + hq*8);
    floatx16 acc[2];
    #pragma unroll
    for(int i = 0; i < 2; ++i)
        #pragma unroll
        for(int r = 0; r < 16; ++r) acc[i][r] = 0.f;
    #pragma unroll
    for(int jt2 = 0; jt2 < 2; ++jt2){
        int jt = j0 + (jh*2 + jt2)*32;
        #pragma unroll
        for(int ks = 0; ks < 6; ++ks){
            short8 af = *(const short8*)((const short*)w1b
                          + (size_t)(jt + lm)*96 + ks*16 + hq*8);
            acc[jt2] = __builtin_amdgcn_mfma_f32_32x32x16_bf16(af, hf[ks], acc[jt2], 0,0,0);
        }
    }
    #pragma unroll
    for(int jt2 = 0; jt2 < 2; ++jt2){
        int jt = j0 + (jh*2 + jt2)*32;
        #pragma unroll
        for(int q = 0; q < 4; ++q){
            float4 bv = *(const float4*)(b1 + jt + 8*q + 4*hq);
            float vr[4] = {acc[jt2][4*q+0] + bv.x, acc[jt2][4*q+1] + bv.y,
                           acc[jt2][4*q+2] + bv.z, acc[jt2][4*q+3] + bv.w};
            short4v pk;
            #pragma unroll
            for(int r = 0; r < 4; ++r) pk[r] = f2bs(vr[r] > 0.f ? vr[r] : 0.f);
            int ks = (jt >> 4) + (q >> 1);
            size_t off = ((((size_t)ks*MBT + mb)*2 + (q & 1))*32 + lm)*8 + 4*hq;
            *(short4v*)((short*)sblk + off) = pk;
        }
    }
}

// ---------------- K5b: FF2, 32 rows/block, 4-way K split, prefetched ----------------
__global__ __launch_bounds__(256) void ff2_kernel(
    const bf16* __restrict__ sblk, const bf16* __restrict__ w2b,
    const float* __restrict__ b2, const float* __restrict__ h1,
    float* __restrict__ h2pre, int row_off, int MBT){
    __shared__ float red[9216];   // waves 1..3 partials: 3 x 3ct x 1024
    const int w = threadIdx.x >> 6, lane = threadIdx.x & 63;
    const int lm = lane & 31, hq = lane >> 5;
    const int r0 = row_off + blockIdx.x*32;
    const int mb = blockIdx.x;
    const short* sbase = (const short*)sblk;
    const short* wbase = (const short*)w2b;
    floatx16 acc[3];
    #pragma unroll
    for(int i = 0; i < 3; ++i)
        #pragma unroll
        for(int r = 0; r < 16; ++r) acc[i][r] = 0.f;
    const int ks0 = w*32;
    #define LD_S(ks) (*(const short8*)(sbase + ((((size_t)(ks)*MBT + mb)*2 + hq)*32 + lm)*8))
    #define LD_W(ct,ks) (*(const short8*)(wbase + (size_t)((ct)*32 + lm)*FFD + (ks)*16 + hq*8))
    short8 sf = LD_S(ks0);
    short8 w0 = LD_W(0, ks0), w1 = LD_W(1, ks0), w2v = LD_W(2, ks0);
    #pragma unroll 4
    for(int i = 1; i < 32; ++i){
        short8 sfn = LD_S(ks0 + i);
        short8 w0n = LD_W(0, ks0 + i);
        short8 w1n = LD_W(1, ks0 + i);
        short8 w2n = LD_W(2, ks0 + i);
        acc[0] = __builtin_amdgcn_mfma_f32_32x32x16_bf16(w0, sf, acc[0], 0,0,0);
        acc[1] = __builtin_amdgcn_mfma_f32_32x32x16_bf16(w1, sf, acc[1], 0,0,0);
        acc[2] = __builtin_amdgcn_mfma_f32_32x32x16_bf16(w2v, sf, acc[2], 0,0,0);
        sf = sfn; w0 = w0n; w1 = w1n; w2v = w2n;
    }
    acc[0] = __builtin_amdgcn_mfma_f32_32x32x16_bf16(w0, sf, acc[0], 0,0,0);
    acc[1] = __builtin_amdgcn_mfma_f32_32x32x16_bf16(w1, sf, acc[1], 0,0,0);
    acc[2] = __builtin_amdgcn_mfma_f32_32x32x16_bf16(w2v, sf, acc[2], 0,0,0);
    #undef LD_S
    #undef LD_W
    if(w > 0){
        #pragma unroll
        for(int ct = 0; ct < 3; ++ct)
            #pragma unroll
            for(int q = 0; q < 4; ++q){
                float4 v;
                v.x = acc[ct][4*q+0]; v.y = acc[ct][4*q+1];
                v.z = acc[ct][4*q+2]; v.w = acc[ct][4*q+3];
                *(float4*)(red + (w-1)*3072 + ct*1024 + lane*16 + 4*q) = v;
            }
    }
    __syncthreads();
    if(w == 0){
        int row = r0 + lm;
        #pragma unroll
        for(int ct = 0; ct < 3; ++ct){
            #pragma unroll
            for(int q = 0; q < 4; ++q){
                int c = ct*32 + 8*q + 4*hq;
                float4 r1 = *(const float4*)(red +      ct*1024 + lane*16 + 4*q);
                float4 r2 = *(const float4*)(red + 3072 + ct*1024 + lane*16 + 4*q);
                float4 r3 = *(const float4*)(red + 6144 + ct*1024 + lane*16 + 4*q);
                float4 b2v = *(const float4*)(b2 + c);
                float4 res = *(const float4*)(h1 + (size_t)row*96 + c);
                float4 o;
                o.x = acc[ct][4*q+0] + r1.x + r2.x + r3.x + b2v.x + res.x;
                o.y = acc[ct][4*q+1] + r1.y + r2.y + r3.y + b2v.y + res.y;
                o.z = acc[ct][4*q+2] + r1.z + r2.z + r3.z + b2v.z + res.z;
                o.w = acc[ct][4*q+3] + r1.w + r2.w + r3.w + b2v.w + res.w;
                *(float4*)(h2pre + (size_t)row*96 + c) = o;
            }
        }
    }
}

// ---------------- K5-fallback: fused FF (only if ws too small) ----------------
__global__ __launch_bounds__(256) void ff_fused_kernel(
    const bf16* __restrict__ h1b, const float* __restrict__ h1,
    const bf16* __restrict__ w1b, const float* __restrict__ b1,
    const bf16* __restrict__ w2b, const float* __restrict__ b2,
    float* __restrict__ h2pre){
    __shared__ __align__(16) char smem[26624 + 26112 + 17408];
    bf16* w1t = (bf16*)smem;
    bf16* w2t = (bf16*)(smem + 26624);
    bf16* sst = (bf16*)(smem + 26624 + 26112);
    float* red = (float*)smem;
    const int tid = threadIdx.x;
    const int w = tid >> 6, lane = tid & 63;
    const int lm = lane & 31, hq = lane >> 5;
    const int r0 = blockIdx.x * 64;
    const int mt2 = w & 1, kh = w >> 1;
    short8 hf[2][6];
    #pragma unroll
    for(int mt = 0; mt < 2; ++mt)
        #pragma unroll
        for(int ks = 0; ks < 6; ++ks)
            hf[mt][ks] = *(const short8*)((const short*)h1b
                          + (size_t)(r0 + mt*32 + lm)*96 + ks*16 + hq*8);
    floatx16 acc2[3];
    #pragma unroll
    for(int i = 0; i < 3; ++i)
        #pragma unroll
        for(int r = 0; r < 16; ++r) acc2[i][r] = 0.f;
    for(int jt = 0; jt < 16; ++jt){
        const int j0 = jt * 128;
        __syncthreads();
        #pragma unroll
        for(int i = 0; i < 6; ++i){
            int e = tid + i*256;
            int row = e/12, c8 = e%12;
            uint4 v = *(const uint4*)((const short*)w1b + (size_t)(j0+row)*96 + c8*8);
            *(uint4*)((short*)w1t + row*104 + c8*8) = v;
        }
        #pragma unroll
        for(int i = 0; i < 6; ++i){
            int e = tid + i*256;
            int row = e/16, j8 = e%16;
            uint4 v = *(const uint4*)((const short*)w2b + (size_t)row*FFD + j0 + j8*8);
            *(uint4*)((short*)w2t + row*136 + j8*8) = v;
        }
        __syncthreads();
        floatx16 a0, a1;
        #pragma unroll
        for(int r = 0; r < 16; ++r){ a0[r] = 0.f; a1[r] = 0.f; }
        #pragma unroll
        for(int ks = 0; ks < 6; ++ks){
            short8 wf = *(const short8*)((const short*)w1t + (w*32+lm)*104 + ks*16 + hq*8);
            a0 = __builtin_amdgcn_mfma_f32_32x32x16_bf16(wf, hf[0][ks], a0, 0, 0, 0);
            a1 = __builtin_amdgcn_mfma_f32_32x32x16_bf16(wf, hf[1][ks], a1, 0, 0, 0);
        }
        #pragma unroll
        for(int q = 0; q < 4; ++q){
            float4 bs = *(const float4*)(b1 + j0 + w*32 + 8*q + 4*hq);
            float bsv[4] = {bs.x, bs.y, bs.z, bs.w};
            short4v p0, p1;
            #pragma unroll
            for(int r = 0; r < 4; ++r){
                float v0 = a0[4*q+r] + bsv[r]; v0 = v0 > 0.f ? v0 : 0.f;
                float v1 = a1[4*q+r] + bsv[r]; v1 = v1 > 0.f ? v1 : 0.f;
                p0[r] = f2bs(v0); p1[r] = f2bs(v1);
            }
            *(short4v*)((short*)sst + lm*136      + w*32 + 8*q + 4*hq) = p0;
            *(short4v*)((short*)sst + (32+lm)*136 + w*32 + 8*q + 4*hq) = p1;
        }
        __syncthreads();
        #pragma unroll
        for(int ks = 0; ks < 4; ++ks){
            int ksg = kh*4 + ks;
            short8 sf = *(const short8*)((const short*)sst + (mt2*32+lm)*136 + ksg*16 + hq*8);
            #pragma unroll
            for(int cct = 0; cct < 3; ++cct){
                short8 wf2 = *(const short8*)((const short*)w2t + (cct*32+lm)*136 + ksg*16 + hq*8);
                acc2[cct] = __builtin_amdgcn_mfma_f32_32x32x16_bf16(wf2, sf, acc2[cct], 0, 0, 0);
            }
        }
    }
    __syncthreads();
    if(kh == 1){
        #pragma unroll
        for(int cct = 0; cct < 3; ++cct)
            #pragma unroll
            for(int q = 0; q < 4; ++q){
                float4 v;
                v.x = acc2[cct][4*q+0]; v.y = acc2[cct][4*q+1];
                v.z = acc2[cct][4*q+2]; v.w = acc2[cct][4*q+3];
                *(float4*)(red + mt2*3072 + cct*1024 + lane*16 + 4*q) = v;
            }
    }
    __syncthreads();
    if(kh == 0){
        int row = r0 + mt2*32 + lm;
        #pragma unroll
        for(int cct = 0; cct < 3; ++cct){
            #pragma unroll
            for(int q = 0; q < 4; ++q){
                int c = cct*32 + 8*q + 4*hq;
                float4 rv  = *(const float4*)(red + mt2*3072 + cct*1024 + lane*16 + 4*q);
                float4 b2v = *(const float4*)(b2 + c);
                float4 res = *(const float4*)(h1 + (size_t)row*96 + c);
                float4 o;
                o.x = acc2[cct][4*q+0] + rv.x + b2v.x + res.x;
                o.y = acc2[cct][4*q+1] + rv.y + b2v.y + res.y;
                o.z = acc2[cct][4*q+2] + rv.z + b2v.z + res.z;
                o.w = acc2[cct][4*q+3] + rv.w + b2v.w + res.w;
                *(float4*)(h2pre + (size_t)row*96 + c) = o;
            }
        }
    }
}

// ---------------- K6: LN2 -> LNf -> transpose -> fp32 out ----------------
__global__ void ln2f_kernel(const float* __restrict__ in, const float* __restrict__ g2,
                            const float* __restrict__ bt2, const float* __restrict__ gf,
                            const float* __restrict__ btf, float* __restrict__ out){
    __shared__ float zt[96*65];
    int wave = threadIdx.x/64, lane = threadIdx.x%64;
    int r0 = blockIdx.x*64;
    for(int rw = 0; rw < 16; ++rw){
        int tt = wave*16 + rw;
        size_t row = (size_t)r0 + tt;
        const float* p = in + row*96;
        float v0 = p[lane];
        float v1 = (lane < 32) ? p[64 + lane] : 0.f;
        float s = v0 + v1;
        for(int off = 32; off; off >>= 1) s += __shfl_down(s, off);
        s = __shfl(s, 0);
        float mu = s*(1.0f/96.0f);
        float d0 = v0 - mu, d1 = (lane < 32) ? (v1 - mu) : 0.f;
        float q = d0*d0 + d1*d1;
        for(int off = 32; off; off >>= 1) q += __shfl_down(q, off);
        q = __shfl(q, 0);
        float rstd = rsqrtf(q*(1.0f/96.0f) + 1e-5f);
        float y0 = d0*rstd*g2[lane] + bt2[lane];
        float y1 = (lane < 32) ? (d1*rstd*g2[64 + lane] + bt2[64 + lane]) : 0.f;
        s = y0 + y1;
        for(int off = 32; off; off >>= 1) s += __shfl_down(s, off);
        s = __shfl(s, 0);
        mu = s*(1.0f/96.0f);
        d0 = y0 - mu; d1 = (lane < 32) ? (y1 - mu) : 0.f;
        q = d0*d0 + d1*d1;
        for(int off = 32; off; off >>= 1) q += __shfl_down(q, off);
        q = __shfl(q, 0);
        rstd = rsqrtf(q*(1.0f/96.0f) + 1e-5f);
        zt[lane*65 + tt] = d0*rstd*gf[lane] + btf[lane];
        if(lane < 32)
            zt[(64 + lane)*65 + tt] = d1*rstd*gf[64 + lane] + btf[64 + lane];
    }
    __syncthreads();
    int b  = r0 / T;
    int t0 = r0 % T;
    for(int e = threadIdx.x; e < 96*64; e += 256){
        int c = e/64, tt = e%64;
        out[(size_t)b*C*T + (size_t)c*T + t0 + tt] = zt[c*65 + tt];
    }
}

extern "C" void kernel_launch(void* const* d_in, const int* in_sizes, int n_in,
                              void* d_out, int out_size, void* d_ws, size_t ws_size,
                              hipStream_t stream) {
    const float* x     = (const float*)d_in[0];
    const float* w_qkv = (const float*)d_in[1];
    const float* b_qkv = (const float*)d_in[2];
    const float* w_out = (const float*)d_in[3];
    const float* b_out = (const float*)d_in[4];
    const float* ln1_g = (const float*)d_in[5];
    const float* ln1_b = (const float*)d_in[6];
    const float* w_ff1 = (const float*)d_in[7];
    const float* b_ff1 = (const float*)d_in[8];
    const float* w_ff2 = (const float*)d_in[9];
    const float* b_ff2 = (const float*)d_in[10];
    const float* ln2_g = (const float*)d_in[11];
    const float* ln2_b = (const float*)d_in[12];
    const float* lnf_g = (const float*)d_in[13];
    const float* lnf_b = (const float*)d_in[14];
    float* out = (float*)d_out;

    char* wsb = (char*)d_ws;
    bf16*  qkvb  = (bf16*)wsb;
    float* xt    = (float*)(wsb + 9437184);
    bf16*  ctxb  = (bf16*)(wsb + 15728640);
    float* h1pre = (float*)wsb;
    float* h1    = (float*)(wsb + 6291456);
    bf16*  h1b   = (bf16*)(wsb + 12582912);
    float* h2pre = (float*)(wsb + 15728640);
    bf16*  wts   = (bf16*)(wsb + 22020096);
    bf16*  wqkvb = wts;
    bf16*  woutb = wts + 27648;
    bf16*  w1b   = wts + 36864;
    bf16*  w2b   = wts + 233472;
    bf16*  sblk  = (bf16*)(wsb + 22880256);

    const size_t base = 22880256;
    int passes = 0;
    if     (ws_size >= base + (size_t)67108864) passes = 1;
    else if(ws_size >= base + (size_t)33554432) passes = 2;
    else if(ws_size >= base + (size_t)16777216) passes = 4;
    else if(ws_size >= base + (size_t) 8388608) passes = 8;

    cvtw_kernel   <<<1680, 256, 0, stream>>>(w_qkv, w_out, w_ff1, w_ff2, wts);
    qkv_kernel    <<<BT/32, 256, 0, stream>>>(x, wqkvb, b_qkv, qkvb, xt);
    attn_kernel   <<<B*NH*(T/128), 256, 0, stream>>>(qkvb, ctxb);
    outproj_kernel<<<BT/64, 256, 0, stream>>>(ctxb, woutb, b_out, xt, h1pre);
    ln_kernel     <<<BT/4, 256, 0, stream>>>(h1pre, ln1_g, ln1_b, h1, h1b);
    if(passes > 0){
        int RPP = BT / passes;
        int nmb = RPP / 64;
        int MBT = RPP / 32;
        for(int p = 0; p < passes; ++p){
            int row_off = p * RPP;
            ff1_kernel<<<nmb*16, 256, 0, stream>>>(h1b, w1b, b_ff1, sblk, row_off, nmb, MBT);
            ff2_kernel<<<MBT, 256, 0, stream>>>(sblk, w2b, b_ff2, h1, h2pre, row_off, MBT);
        }
    } else {
        ff_fused_kernel<<<BT/64, 256, 0, stream>>>(h1b, h1, w1b, b_ff1, w2b, b_ff2, h2pre);
    }
    ln2f_kernel   <<<BT/64, 256, 0, stream>>>(h2pre, ln2_g, ln2_b, lnf_g, lnf_b, out);
}

// Round 6
// 174.656 us; speedup vs baseline: 4.8810x; 1.1795x over previous
//
#include <hip/hip_runtime.h>
#include <hip/hip_bf16.h>

#define B 8
#define T 2048
#define C 96
#define NH 3
#define HD 32
#define FFD 2048
#define HALF_W 32
#define BT (B*T)

typedef __hip_bfloat16 bf16;
typedef __attribute__((ext_vector_type(8))) short short8;
typedef __attribute__((ext_vector_type(4))) short short4v;
typedef __attribute__((ext_vector_type(16))) float floatx16;

__device__ __forceinline__ short f2bs(float v){
    __hip_bfloat16 h = __float2bfloat16(v);
    return *reinterpret_cast<short*>(&h);
}
__device__ __forceinline__ int imin(int a, int b){ return a < b ? a : b; }
__device__ __forceinline__ int imax(int a, int b){ return a > b ? a : b; }
__device__ __forceinline__ short8 ld_b64x2(const short* p){
    short4v a = *(const short4v*)p;
    short4v b = *(const short4v*)(p + 4);
    short8 v;
    v[0]=a[0]; v[1]=a[1]; v[2]=a[2]; v[3]=a[3];
    v[4]=b[0]; v[5]=b[1]; v[6]=b[2]; v[7]=b[3];
    return v;
}

// ---------------- K0: convert all weights to bf16 ----------------
__global__ void cvtw_kernel(const float* __restrict__ wq, const float* __restrict__ wo,
                            const float* __restrict__ w1, const float* __restrict__ w2,
                            bf16* __restrict__ dst){
    int i = blockIdx.x*256 + threadIdx.x;
    if(i < 27648)       dst[i] = __float2bfloat16(wq[i]);
    else if(i < 36864)  dst[i] = __float2bfloat16(wo[i-27648]);
    else if(i < 233472) dst[i] = __float2bfloat16(w1[i-36864]);
    else if(i < 430080) dst[i] = __float2bfloat16(w2[i-233472]);
}

// ---------------- K1: QKV projection, MFMA; Q/K/V stored [type][b][h][t][32] ----------------
__global__ __launch_bounds__(256) void qkv_kernel(
    const float* __restrict__ x, const bf16* __restrict__ wq,
    const float* __restrict__ bias, bf16* __restrict__ qkvs, float* __restrict__ xt){
    __shared__ float xs[96*36];   // [c][t], stride 36
    int b  = blockIdx.x >> 6;            // T/32 = 64 tiles per batch
    int t0 = (blockIdx.x & 63) * 32;
    for(int e = threadIdx.x; e < 96*8; e += 256){
        int c = e >> 3, t4 = e & 7;
        *(float4*)(xs + c*36 + t4*4) =
            *(const float4*)(x + (size_t)b*C*T + (size_t)c*T + t0 + t4*4);
    }
    __syncthreads();
    int r0 = b*T + t0;
    for(int e = threadIdx.x; e < 768; e += 256){
        int t = e/24, c4 = e%24;
        float4 v;
        v.x = xs[(c4*4+0)*36 + t]; v.y = xs[(c4*4+1)*36 + t];
        v.z = xs[(c4*4+2)*36 + t]; v.w = xs[(c4*4+3)*36 + t];
        *(float4*)(xt + (size_t)(r0 + t)*96 + c4*4) = v;
    }
    const int w = threadIdx.x >> 6, lane = threadIdx.x & 63;
    const int lm = lane & 31, hq = lane >> 5;
    short8 bfr[6];
    #pragma unroll
    for(int ks = 0; ks < 6; ++ks){
        short8 v;
        #pragma unroll
        for(int i = 0; i < 8; ++i)
            v[i] = f2bs(xs[(ks*16 + hq*8 + i)*36 + lm]);
        bfr[ks] = v;
    }
    int nacc = (w == 0) ? 3 : 2;
    int ots[3] = {w, w+4, 8};
    floatx16 acc[3];
    #pragma unroll
    for(int i = 0; i < 3; ++i)
        #pragma unroll
        for(int r = 0; r < 16; ++r) acc[i][r] = 0.f;
    #pragma unroll
    for(int i = 0; i < 3; ++i){
        if(i < nacc){
            #pragma unroll
            for(int ks = 0; ks < 6; ++ks){
                short8 af = *(const short8*)((const short*)wq
                              + (size_t)(ots[i]*32 + lm)*96 + ks*16 + hq*8);
                acc[i] = __builtin_amdgcn_mfma_f32_32x32x16_bf16(af, bfr[ks], acc[i], 0,0,0);
            }
        }
    }
    // D: col=lm=token, reg->o_local. Store [type][b][h][t][32] (line-covered rows)
    #pragma unroll
    for(int i = 0; i < 3; ++i){
        if(i < nacc){
            int type = ots[i]/3, hh = ots[i]%3;
            size_t rowbase = (((size_t)type*B*NH) + (size_t)b*NH + hh)*T + t0 + lm;
            #pragma unroll
            for(int q = 0; q < 4; ++q){
                float4 bv = *(const float4*)(bias + ots[i]*32 + 8*q + 4*hq);
                short4v pk;
                pk[0] = f2bs(acc[i][4*q+0] + bv.x);
                pk[1] = f2bs(acc[i][4*q+1] + bv.y);
                pk[2] = f2bs(acc[i][4*q+2] + bv.z);
                pk[3] = f2bs(acc[i][4*q+3] + bv.w);
                *(short4v*)((short*)qkvs + rowbase*32 + 8*q + 4*hq) = pk;
            }
        }
    }
}

// ---------------- K2: banded attention via MFMA, 64-query blocks ----------------
// grid B*NH*(T/64), block 128 (2 waves). Wave w: queries [t0+32w, t0+32w+32).
// LDS strides chosen conflict-free (word-stride ~ odd*2): VtS 132, PtS 100.
__global__ __launch_bounds__(128) void attn_kernel(const bf16* __restrict__ qkvs,
                                                   bf16* __restrict__ ctxh){
    __shared__ __align__(16) short VtS[32*132];     // V^T [d][key 0..127]
    __shared__ __align__(16) short PtS[2][32*100];  // per wave: P [query][key 0..95]
    __shared__ float LsS[2][32];
    int blk = blockIdx.x;
    int ntile = T/64;  // 32
    int b   = blk / (NH*ntile);
    int rem = blk % (NH*ntile);
    int h   = rem / ntile;
    int t0  = (rem % ntile) * 64;
    const short* qb = (const short*)qkvs + ((size_t)0*B*NH + (size_t)b*NH + h)*T*32;
    const short* kb = (const short*)qkvs + ((size_t)1*B*NH + (size_t)b*NH + h)*T*32;
    const short* vb = (const short*)qkvs + ((size_t)2*B*NH + (size_t)b*NH + h)*T*32;
    const int tid = threadIdx.x;
    const int w = tid >> 6, lane = tid & 63;
    const int lm = lane & 31, hq = lane >> 5;

    // stage V^T: 128 keys, s = t0-32+kk (clamped; mask kills OOB)
    for(int e = tid; e < 256; e += 128){
        int kp = e >> 2, d8 = e & 3;          // keys 2kp,2kp+1; dims d8*8..+8
        int sa = imin(imax(t0 - 32 + 2*kp, 0), T-1);
        int sb = imin(imax(t0 - 32 + 2*kp + 1, 0), T-1);
        short8 va = *(const short8*)(vb + (size_t)sa*32 + d8*8);
        short8 v2 = *(const short8*)(vb + (size_t)sb*32 + d8*8);
        #pragma unroll
        for(int j = 0; j < 8; ++j){
            int val = (int)(unsigned short)va[j] | ((int)(unsigned short)v2[j] << 16);
            *(int*)(VtS + (d8*8 + j)*132 + 2*kp) = val;
        }
    }
    // ---- S phase: Q (B-frag), K (A-frag), direct from global (64 B rows)
    short8 qf0, qf1;
    {
        const short* qrow = qb + (size_t)(t0 + 32*w + lm)*32;
        qf0 = *(const short8*)(qrow + hq*8);
        qf1 = *(const short8*)(qrow + 16 + hq*8);
    }
    floatx16 S[3];
    #pragma unroll
    for(int sub = 0; sub < 3; ++sub){
        int srow = imin(imax(t0 + 32*w - 32 + sub*32 + lm, 0), T-1);
        const short* krow = kb + (size_t)srow*32;
        short8 kf0 = *(const short8*)(krow + hq*8);
        short8 kf1 = *(const short8*)(krow + 16 + hq*8);
        floatx16 z;
        #pragma unroll
        for(int r = 0; r < 16; ++r) z[r] = 0.f;
        z = __builtin_amdgcn_mfma_f32_32x32x16_bf16(kf0, qf0, z, 0,0,0);
        z = __builtin_amdgcn_mfma_f32_32x32x16_bf16(kf1, qf1, z, 0,0,0);
        S[sub] = z;
    }
    // ---- masked exp + per-query sums. D: col=query=lm, reg->key.
    const float scale = 0.17677669529663687f;
    float part = 0.f;
    #pragma unroll
    for(int sub = 0; sub < 3; ++sub){
        #pragma unroll
        for(int r = 0; r < 16; ++r){
            int key_local = sub*32 + (r&3) + 8*(r>>2) + 4*hq;
            int s_glob = t0 + 32*w - 32 + key_local;
            int rel = key_local - lm;
            bool ok = (rel >= 0) && (rel <= 64) && (s_glob >= 0) && (s_glob < T);
            float p = ok ? __expf(S[sub][r]*scale) : 0.f;
            S[sub][r] = p;
            part += p;
        }
    }
    float ltot = part + __shfl_xor(part, 32);
    if(hq == 0) LsS[w][lm] = ltot;
    // ---- P -> LDS transposed: Pt[query=lm][key_local]
    #pragma unroll
    for(int sub = 0; sub < 3; ++sub){
        #pragma unroll
        for(int q4 = 0; q4 < 4; ++q4){
            int kbase = sub*32 + 8*q4 + 4*hq;
            short4v pk;
            pk[0] = f2bs(S[sub][4*q4+0]);
            pk[1] = f2bs(S[sub][4*q4+1]);
            pk[2] = f2bs(S[sub][4*q4+2]);
            pk[3] = f2bs(S[sub][4*q4+3]);
            *(short4v*)(PtS[w] + lm*100 + kbase) = pk;
        }
    }
    __syncthreads();
    // ---- PV: O[q][d] = sum_k P[q][k] V[k][d]; A=Pt rows (q=lm), B=Vt rows (d=lm)
    floatx16 O;
    #pragma unroll
    for(int r = 0; r < 16; ++r) O[r] = 0.f;
    #pragma unroll
    for(int ks = 0; ks < 6; ++ks){
        short8 pa = ld_b64x2(PtS[w] + lm*100 + ks*16 + hq*8);
        short8 vf = ld_b64x2(VtS + lm*132 + 32*w + ks*16 + hq*8);
        O = __builtin_amdgcn_mfma_f32_32x32x16_bf16(pa, vf, O, 0,0,0);
    }
    // ---- epilogue: /l, write ctxh[b][h][t][32]. D: col=lm=d, reg->query.
    #pragma unroll
    for(int r = 0; r < 16; ++r){
        int qr = (r&3) + 8*(r>>2) + 4*hq;
        float linv = 1.f / LsS[w][qr];
        ((short*)ctxh)[(((size_t)b*NH + h)*T + t0 + 32*w + qr)*32 + lm] = f2bs(O[r]*linv);
    }
}

// ---------------- K3: outproj + residual + LN1 fused ----------------
// grid BT/32, block 192 (3 waves, wave = ct). Writes h1 (fp32) + h1b (bf16).
__global__ __launch_bounds__(192) void outproj_ln_kernel(
    const bf16* __restrict__ ctxh, const bf16* __restrict__ wo,
    const float* __restrict__ bias, const float* __restrict__ xt,
    const float* __restrict__ g1, const float* __restrict__ bb1,
    float* __restrict__ h1, bf16* __restrict__ h1b){
    __shared__ float red[2][3][32];
    const int ct = threadIdx.x >> 6, lane = threadIdx.x & 63;
    const int lm = lane & 31, hq = lane >> 5;
    const int r0 = blockIdx.x * 32;
    const int b = r0 / T, tloc = r0 % T;
    // B-frag: token r0+lm, c-chunk ks*16+hq*8 -> (head, d)
    short8 bfr[6];
    #pragma unroll
    for(int ks = 0; ks < 6; ++ks){
        int off = ks*16 + hq*8;
        int hh = off >> 5, dd = off & 31;
        bfr[ks] = *(const short8*)((const short*)ctxh
                    + (((size_t)b*NH + hh)*T + tloc + lm)*32 + dd);
    }
    floatx16 acc;
    #pragma unroll
    for(int r = 0; r < 16; ++r) acc[r] = 0.f;
    #pragma unroll
    for(int ks = 0; ks < 6; ++ks){
        short8 af = *(const short8*)((const short*)wo
                      + (size_t)(ct*32 + lm)*96 + ks*16 + hq*8);
        acc = __builtin_amdgcn_mfma_f32_32x32x16_bf16(af, bfr[ks], acc, 0,0,0);
    }
    // epilogue: row=lm, c = ct*32 + 8q+4hq + r
    float vals[16];
    float p1 = 0.f, p2 = 0.f;
    #pragma unroll
    for(int q = 0; q < 4; ++q){
        int c = ct*32 + 8*q + 4*hq;
        float4 bv = *(const float4*)(bias + c);
        float4 xv = *(const float4*)(xt + (size_t)(r0 + lm)*96 + c);
        float bva[4] = {bv.x, bv.y, bv.z, bv.w};
        float xva[4] = {xv.x, xv.y, xv.z, xv.w};
        #pragma unroll
        for(int r = 0; r < 4; ++r){
            float v = acc[4*q+r] + bva[r] + xva[r];
            vals[4*q+r] = v;
            p1 += v; p2 += v*v;
        }
    }
    p1 += __shfl_xor(p1, 32);
    p2 += __shfl_xor(p2, 32);
    if(hq == 0){ red[0][ct][lm] = p1; red[1][ct][lm] = p2; }
    __syncthreads();
    float s  = red[0][0][lm] + red[0][1][lm] + red[0][2][lm];
    float s2 = red[1][0][lm] + red[1][1][lm] + red[1][2][lm];
    float mu = s * (1.0f/96.0f);
    float rstd = rsqrtf(s2*(1.0f/96.0f) - mu*mu + 1e-5f);
    int row = r0 + lm;
    #pragma unroll
    for(int q = 0; q < 4; ++q){
        int c = ct*32 + 8*q + 4*hq;
        float4 gv = *(const float4*)(g1 + c);
        float4 bv = *(const float4*)(bb1 + c);
        float ga[4] = {gv.x, gv.y, gv.z, gv.w};
        float ba[4] = {bv.x, bv.y, bv.z, bv.w};
        float4 yo;
        float ya[4];
        #pragma unroll
        for(int r = 0; r < 4; ++r)
            ya[r] = (vals[4*q+r] - mu)*rstd*ga[r] + ba[r];
        yo.x = ya[0]; yo.y = ya[1]; yo.z = ya[2]; yo.w = ya[3];
        *(float4*)(h1 + (size_t)row*96 + c) = yo;
        short4v pk;
        #pragma unroll
        for(int r = 0; r < 4; ++r) pk[r] = f2bs(ya[r]);
        *(short4v*)((short*)h1b + (size_t)row*96 + c) = pk;
    }
}

// ---------------- K5a: FF1 -> blocked bf16 s, barrier-free ----------------
__global__ __launch_bounds__(256) void ff1_kernel(
    const bf16* __restrict__ h1b, const bf16* __restrict__ w1b,
    const float* __restrict__ b1, bf16* __restrict__ sblk,
    int row_off, int nmb, int MBT){
    const int jblk = blockIdx.x / nmb;
    const int mblk = blockIdx.x % nmb;
    const int w = threadIdx.x >> 6, lane = threadIdx.x & 63;
    const int lm = lane & 31, hq = lane >> 5;
    const int mt = w & 1, jh = w >> 1;
    const int r0 = row_off + mblk*64;
    const int j0 = jblk*128;
    const int mb = mblk*2 + mt;
    short8 hf[6];
    #pragma unroll
    for(int ks = 0; ks < 6; ++ks)
        hf[ks] = *(const short8*)((const short*)h1b
                   + (size_t)(r0 + mt*32 + lm)*96 + ks*16 + hq*8);
    floatx16 acc[2];
    #pragma unroll
    for(int i = 0; i < 2; ++i)
        #pragma unroll
        for(int r = 0; r < 16; ++r) acc[i][r] = 0.f;
    #pragma unroll
    for(int jt2 = 0; jt2 < 2; ++jt2){
        int jt = j0 + (jh*2 + jt2)*32;
        #pragma unroll
        for(int ks = 0; ks < 6; ++ks){
            short8 af = *(const short8*)((const short*)w1b
                          + (size_t)(jt + lm)*96 + ks*16 + hq*8);
            acc[jt2] = __builtin_amdgcn_mfma_f32_32x32x16_bf16(af, hf[ks], acc[jt2], 0,0,0);
        }
    }
    #pragma unroll
    for(int jt2 = 0; jt2 < 2; ++jt2){
        int jt = j0 + (jh*2 + jt2)*32;
        #pragma unroll
        for(int q = 0; q < 4; ++q){
            float4 bv = *(const float4*)(b1 + jt + 8*q + 4*hq);
            float vr[4] = {acc[jt2][4*q+0] + bv.x, acc[jt2][4*q+1] + bv.y,
                           acc[jt2][4*q+2] + bv.z, acc[jt2][4*q+3] + bv.w};
            short4v pk;
            #pragma unroll
            for(int r = 0; r < 4; ++r) pk[r] = f2bs(vr[r] > 0.f ? vr[r] : 0.f);
            int ks = (jt >> 4) + (q >> 1);
            size_t off = ((((size_t)ks*MBT + mb)*2 + (q & 1))*32 + lm)*8 + 4*hq;
            *(short4v*)((short*)sblk + off) = pk;
        }
    }
}

// ---------------- K5b: FF2 + residual + LN2 + LNf + transpose-out fused ----------------
// grid RPP/32, block 256 (4 waves = K-quarters), prefetched k-loop.
__global__ __launch_bounds__(256) void ff2_ln_kernel(
    const bf16* __restrict__ sblk, const bf16* __restrict__ w2b,
    const float* __restrict__ b2, const float* __restrict__ h1,
    const float* __restrict__ g2, const float* __restrict__ bt2,
    const float* __restrict__ gf, const float* __restrict__ btf,
    float* __restrict__ out, int row_off, int MBT){
    __shared__ float red[9216];      // waves 1..3 partials
    __shared__ float zt[96*33];      // transposed LN output
    const int w = threadIdx.x >> 6, lane = threadIdx.x & 63;
    const int lm = lane & 31, hq = lane >> 5;
    const int r0 = row_off + blockIdx.x*32;
    const int mb = blockIdx.x;
    const short* sbase = (const short*)sblk;
    const short* wbase = (const short*)w2b;
    floatx16 acc[3];
    #pragma unroll
    for(int i = 0; i < 3; ++i)
        #pragma unroll
        for(int r = 0; r < 16; ++r) acc[i][r] = 0.f;
    const int ks0 = w*32;
    #define LD_S(ks) (*(const short8*)(sbase + ((((size_t)(ks)*MBT + mb)*2 + hq)*32 + lm)*8))
    #define LD_W(ct,ks) (*(const short8*)(wbase + (size_t)((ct)*32 + lm)*FFD + (ks)*16 + hq*8))
    short8 sf = LD_S(ks0);
    short8 w0 = LD_W(0, ks0), w1 = LD_W(1, ks0), w2v = LD_W(2, ks0);
    #pragma unroll 4
    for(int i = 1; i < 32; ++i){
        short8 sfn = LD_S(ks0 + i);
        short8 w0n = LD_W(0, ks0 + i);
        short8 w1n = LD_W(1, ks0 + i);
        short8 w2n = LD_W(2, ks0 + i);
        acc[0] = __builtin_amdgcn_mfma_f32_32x32x16_bf16(w0, sf, acc[0], 0,0,0);
        acc[1] = __builtin_amdgcn_mfma_f32_32x32x16_bf16(w1, sf, acc[1], 0,0,0);
        acc[2] = __builtin_amdgcn_mfma_f32_32x32x16_bf16(w2v, sf, acc[2], 0,0,0);
        sf = sfn; w0 = w0n; w1 = w1n; w2v = w2n;
    }
    acc[0] = __builtin_amdgcn_mfma_f32_32x32x16_bf16(w0, sf, acc[0], 0,0,0);
    acc[1] = __builtin_amdgcn_mfma_f32_32x32x16_bf16(w1, sf, acc[1], 0,0,0);
    acc[2] = __builtin_amdgcn_mfma_f32_32x32x16_bf16(w2v, sf, acc[2], 0,0,0);
    #undef LD_S
    #undef LD_W
    if(w > 0){
        #pragma unroll
        for(int ct = 0; ct < 3; ++ct)
            #pragma unroll
            for(int q = 0; q < 4; ++q){
                float4 v;
                v.x = acc[ct][4*q+0]; v.y = acc[ct][4*q+1];
                v.z = acc[ct][4*q+2]; v.w = acc[ct][4*q+3];
                *(float4*)(red + (w-1)*3072 + ct*1024 + lane*16 + 4*q) = v;
            }
    }
    __syncthreads();
    if(w == 0){
        // token = lm; lane holds 48 c-values: c = ct*32 + 8q + 4hq + r
        float vals[48];
        float p1 = 0.f, p2 = 0.f;
        #pragma unroll
        for(int ct = 0; ct < 3; ++ct){
            #pragma unroll
            for(int q = 0; q < 4; ++q){
                int c = ct*32 + 8*q + 4*hq;
                float4 r1 = *(const float4*)(red +        ct*1024 + lane*16 + 4*q);
                float4 r2 = *(const float4*)(red + 3072 + ct*1024 + lane*16 + 4*q);
                float4 r3 = *(const float4*)(red + 6144 + ct*1024 + lane*16 + 4*q);
                float4 bv = *(const float4*)(b2 + c);
                float4 rs = *(const float4*)(h1 + (size_t)(r0 + lm)*96 + c);
                float ra[4] = {r1.x+r2.x+r3.x+bv.x+rs.x, r1.y+r2.y+r3.y+bv.y+rs.y,
                               r1.z+r2.z+r3.z+bv.z+rs.z, r1.w+r2.w+r3.w+bv.w+rs.w};
                #pragma unroll
                for(int r = 0; r < 4; ++r){
                    float v = acc[ct][4*q+r] + ra[r];
                    vals[ct*16 + 4*q + r] = v;
                    p1 += v; p2 += v*v;
                }
            }
        }
        p1 += __shfl_xor(p1, 32);
        p2 += __shfl_xor(p2, 32);
        float mu = p1*(1.0f/96.0f);
        float rstd = rsqrtf(p2*(1.0f/96.0f) - mu*mu + 1e-5f);
        // LN2 -> y, accumulate LNf stats
        float q1 = 0.f, q2 = 0.f;
        #pragma unroll
        for(int ct = 0; ct < 3; ++ct){
            #pragma unroll
            for(int q = 0; q < 4; ++q){
                int c = ct*32 + 8*q + 4*hq;
                float4 gv = *(const float4*)(g2 + c);
                float4 bv = *(const float4*)(bt2 + c);
                float ga[4] = {gv.x, gv.y, gv.z, gv.w};
                float ba[4] = {bv.x, bv.y, bv.z, bv.w};
                #pragma unroll
                for(int r = 0; r < 4; ++r){
                    float y = (vals[ct*16+4*q+r] - mu)*rstd*ga[r] + ba[r];
                    vals[ct*16+4*q+r] = y;
                    q1 += y; q2 += y*y;
                }
            }
        }
        q1 += __shfl_xor(q1, 32);
        q2 += __shfl_xor(q2, 32);
        float mu2 = q1*(1.0f/96.0f);
        float rstd2 = rsqrtf(q2*(1.0f/96.0f) - mu2*mu2 + 1e-5f);
        #pragma unroll
        for(int ct = 0; ct < 3; ++ct){
            #pragma unroll
            for(int q = 0; q < 4; ++q){
                int c = ct*32 + 8*q + 4*hq;
                float4 gv = *(const float4*)(gf + c);
                float4 bv = *(const float4*)(btf + c);
                float ga[4] = {gv.x, gv.y, gv.z, gv.w};
                float ba[4] = {bv.x, bv.y, bv.z, bv.w};
                #pragma unroll
                for(int r = 0; r < 4; ++r)
                    zt[(c + r)*33 + lm] = (vals[ct*16+4*q+r] - mu2)*rstd2*ga[r] + ba[r];
            }
        }
    }
    __syncthreads();
    int bb  = r0 / T;
    int t0g = r0 % T;
    for(int e = threadIdx.x; e < 96*32; e += 256){
        int c = e >> 5, tt = e & 31;
        out[(size_t)bb*C*T + (size_t)c*T + t0g + tt] = zt[c*33 + tt];
    }
}

// ---------------- K5-fallback: fused FF (only if ws too small) ----------------
__global__ __launch_bounds__(256) void ff_fused_kernel(
    const bf16* __restrict__ h1b, const float* __restrict__ h1,
    const bf16* __restrict__ w1b, const float* __restrict__ b1,
    const bf16* __restrict__ w2b, const float* __restrict__ b2,
    float* __restrict__ h2pre){
    __shared__ __align__(16) char smem[26624 + 26112 + 17408];
    bf16* w1t = (bf16*)smem;
    bf16* w2t = (bf16*)(smem + 26624);
    bf16* sst = (bf16*)(smem + 26624 + 26112);
    float* red = (float*)smem;
    const int tid = threadIdx.x;
    const int w = tid >> 6, lane = tid & 63;
    const int lm = lane & 31, hq = lane >> 5;
    const int r0 = blockIdx.x * 64;
    const int mt2 = w & 1, kh = w >> 1;
    short8 hf[2][6];
    #pragma unroll
    for(int mt = 0; mt < 2; ++mt)
        #pragma unroll
        for(int ks = 0; ks < 6; ++ks)
            hf[mt][ks] = *(const short8*)((const short*)h1b
                          + (size_t)(r0 + mt*32 + lm)*96 + ks*16 + hq*8);
    floatx16 acc2[3];
    #pragma unroll
    for(int i = 0; i < 3; ++i)
        #pragma unroll
        for(int r = 0; r < 16; ++r) acc2[i][r] = 0.f;
    for(int jt = 0; jt < 16; ++jt){
        const int j0 = jt * 128;
        __syncthreads();
        #pragma unroll
        for(int i = 0; i < 6; ++i){
            int e = tid + i*256;
            int row = e/12, c8 = e%12;
            uint4 v = *(const uint4*)((const short*)w1b + (size_t)(j0+row)*96 + c8*8);
            *(uint4*)((short*)w1t + row*104 + c8*8) = v;
        }
        #pragma unroll
        for(int i = 0; i < 6; ++i){
            int e = tid + i*256;
            int row = e/16, j8 = e%16;
            uint4 v = *(const uint4*)((const short*)w2b + (size_t)row*FFD + j0 + j8*8);
            *(uint4*)((short*)w2t + row*136 + j8*8) = v;
        }
        __syncthreads();
        floatx16 a0, a1;
        #pragma unroll
        for(int r = 0; r < 16; ++r){ a0[r] = 0.f; a1[r] = 0.f; }
        #pragma unroll
        for(int ks = 0; ks < 6; ++ks){
            short8 wf = *(const short8*)((const short*)w1t + (w*32+lm)*104 + ks*16 + hq*8);
            a0 = __builtin_amdgcn_mfma_f32_32x32x16_bf16(wf, hf[0][ks], a0, 0, 0, 0);
            a1 = __builtin_amdgcn_mfma_f32_32x32x16_bf16(wf, hf[1][ks], a1, 0, 0, 0);
        }
        #pragma unroll
        for(int q = 0; q < 4; ++q){
            float4 bs = *(const float4*)(b1 + j0 + w*32 + 8*q + 4*hq);
            float bsv[4] = {bs.x, bs.y, bs.z, bs.w};
            short4v p0, p1;
            #pragma unroll
            for(int r = 0; r < 4; ++r){
                float v0 = a0[4*q+r] + bsv[r]; v0 = v0 > 0.f ? v0 : 0.f;
                float v1 = a1[4*q+r] + bsv[r]; v1 = v1 > 0.f ? v1 : 0.f;
                p0[r] = f2bs(v0); p1[r] = f2bs(v1);
            }
            *(short4v*)((short*)sst + lm*136      + w*32 + 8*q + 4*hq) = p0;
            *(short4v*)((short*)sst + (32+lm)*136 + w*32 + 8*q + 4*hq) = p1;
        }
        __syncthreads();
        #pragma unroll
        for(int ks = 0; ks < 4; ++ks){
            int ksg = kh*4 + ks;
            short8 sf = *(const short8*)((const short*)sst + (mt2*32+lm)*136 + ksg*16 + hq*8);
            #pragma unroll
            for(int cct = 0; cct < 3; ++cct){
                short8 wf2 = *(const short8*)((const short*)w2t + (cct*32+lm)*136 + ksg*16 + hq*8);
                acc2[cct] = __builtin_amdgcn_mfma_f32_32x32x16_bf16(wf2, sf, acc2[cct], 0, 0, 0);
            }
        }
    }
    __syncthreads();
    if(kh == 1){
        #pragma unroll
        for(int cct = 0; cct < 3; ++cct)
            #pragma unroll
            for(int q = 0; q < 4; ++q){
                float4 v;
                v.x = acc2[cct][4*q+0]; v.y = acc2[cct][4*q+1];
                v.z = acc2[cct][4*q+2]; v.w = acc2[cct][4*q+3];
                *(float4*)(red + mt2*3072 + cct*1024 + lane*16 + 4*q) = v;
            }
    }
    __syncthreads();
    if(kh == 0){
        int row = r0 + mt2*32 + lm;
        #pragma unroll
        for(int cct = 0; cct < 3; ++cct){
            #pragma unroll
            for(int q = 0; q < 4; ++q){
                int c = cct*32 + 8*q + 4*hq;
                float4 rv  = *(const float4*)(red + mt2*3072 + cct*1024 + lane*16 + 4*q);
                float4 b2v = *(const float4*)(b2 + c);
                float4 res = *(const float4*)(h1 + (size_t)row*96 + c);
                float4 o;
                o.x = acc2[cct][4*q+0] + rv.x + b2v.x + res.x;
                o.y = acc2[cct][4*q+1] + rv.y + b2v.y + res.y;
                o.z = acc2[cct][4*q+2] + rv.z + b2v.z + res.z;
                o.w = acc2[cct][4*q+3] + rv.w + b2v.w + res.w;
                *(float4*)(h2pre + (size_t)row*96 + c) = o;
            }
        }
    }
}

// ---------------- K6-fallback: LN2 -> LNf -> transpose -> fp32 out ----------------
__global__ void ln2f_kernel(const float* __restrict__ in, const float* __restrict__ g2,
                            const float* __restrict__ bt2, const float* __restrict__ gf,
                            const float* __restrict__ btf, float* __restrict__ out){
    __shared__ float zt[96*65];
    int wave = threadIdx.x/64, lane = threadIdx.x%64;
    int r0 = blockIdx.x*64;
    for(int rw = 0; rw < 16; ++rw){
        int tt = wave*16 + rw;
        size_t row = (size_t)r0 + tt;
        const float* p = in + row*96;
        float v0 = p[lane];
        float v1 = (lane < 32) ? p[64 + lane] : 0.f;
        float s = v0 + v1;
        for(int off = 32; off; off >>= 1) s += __shfl_down(s, off);
        s = __shfl(s, 0);
        float mu = s*(1.0f/96.0f);
        float d0 = v0 - mu, d1 = (lane < 32) ? (v1 - mu) : 0.f;
        float q = d0*d0 + d1*d1;
        for(int off = 32; off; off >>= 1) q += __shfl_down(q, off);
        q = __shfl(q, 0);
        float rstd = rsqrtf(q*(1.0f/96.0f) + 1e-5f);
        float y0 = d0*rstd*g2[lane] + bt2[lane];
        float y1 = (lane < 32) ? (d1*rstd*g2[64 + lane] + bt2[64 + lane]) : 0.f;
        s = y0 + y1;
        for(int off = 32; off; off >>= 1) s += __shfl_down(s, off);
        s = __shfl(s, 0);
        mu = s*(1.0f/96.0f);
        d0 = y0 - mu; d1 = (lane < 32) ? (y1 - mu) : 0.f;
        q = d0*d0 + d1*d1;
        for(int off = 32; off; off >>= 1) q += __shfl_down(q, off);
        q = __shfl(q, 0);
        rstd = rsqrtf(q*(1.0f/96.0f) + 1e-5f);
        zt[lane*65 + tt] = d0*rstd*gf[lane] + btf[lane];
        if(lane < 32)
            zt[(64 + lane)*65 + tt] = d1*rstd*gf[64 + lane] + btf[64 + lane];
    }
    __syncthreads();
    int b  = r0 / T;
    int t0 = r0 % T;
    for(int e = threadIdx.x; e < 96*64; e += 256){
        int c = e/64, tt = e%64;
        out[(size_t)b*C*T + (size_t)c*T + t0 + tt] = zt[c*65 + tt];
    }
}

extern "C" void kernel_launch(void* const* d_in, const int* in_sizes, int n_in,
                              void* d_out, int out_size, void* d_ws, size_t ws_size,
                              hipStream_t stream) {
    const float* x     = (const float*)d_in[0];
    const float* w_qkv = (const float*)d_in[1];
    const float* b_qkv = (const float*)d_in[2];
    const float* w_out = (const float*)d_in[3];
    const float* b_out = (const float*)d_in[4];
    const float* ln1_g = (const float*)d_in[5];
    const float* ln1_b = (const float*)d_in[6];
    const float* w_ff1 = (const float*)d_in[7];
    const float* b_ff1 = (const float*)d_in[8];
    const float* w_ff2 = (const float*)d_in[9];
    const float* b_ff2 = (const float*)d_in[10];
    const float* ln2_g = (const float*)d_in[11];
    const float* ln2_b = (const float*)d_in[12];
    const float* lnf_g = (const float*)d_in[13];
    const float* lnf_b = (const float*)d_in[14];
    float* out = (float*)d_out;

    // ws map (bytes):
    //   qkvs  [0, 9.44M)           Q/K/V [type][b][h][t][32] bf16
    //   xt    [9.44M, 15.73M)      x transposed fp32
    //   ctxh  [15.73M, 18.87M)     ctx [b][h][t][32] bf16
    //   h1    [18.87M, 25.17M)     fp32
    //   h1b   [25.17M, 28.31M)     bf16
    //   wts   [28.31M, 29.17M)     bf16 weights
    //   sblk  [29.17M, +64M/passes)
    //   (fallback h2pre over dead qkvs at [0, 6.29M))
    char* wsb = (char*)d_ws;
    bf16*  qkvs  = (bf16*)wsb;
    float* xt    = (float*)(wsb + 9437184);
    bf16*  ctxh  = (bf16*)(wsb + 15728640);
    float* h1    = (float*)(wsb + 18874368);
    bf16*  h1b   = (bf16*)(wsb + 25165824);
    bf16*  wts   = (bf16*)(wsb + 28311552);
    bf16*  wqkvb = wts;
    bf16*  woutb = wts + 27648;
    bf16*  w1b   = wts + 36864;
    bf16*  w2b   = wts + 233472;
    bf16*  sblk  = (bf16*)(wsb + 29171712);
    float* h2pre = (float*)wsb;           // fallback only

    const size_t base = 29171712;
    int passes = 0;
    if     (ws_size >= base + (size_t)67108864) passes = 1;
    else if(ws_size >= base + (size_t)33554432) passes = 2;
    else if(ws_size >= base + (size_t)16777216) passes = 4;
    else if(ws_size >= base + (size_t) 8388608) passes = 8;

    cvtw_kernel      <<<1680, 256, 0, stream>>>(w_qkv, w_out, w_ff1, w_ff2, wts);
    qkv_kernel       <<<BT/32, 256, 0, stream>>>(x, wqkvb, b_qkv, qkvs, xt);
    attn_kernel      <<<B*NH*(T/64), 128, 0, stream>>>(qkvs, ctxh);
    outproj_ln_kernel<<<BT/32, 192, 0, stream>>>(ctxh, woutb, b_out, xt,
                                                 ln1_g, ln1_b, h1, h1b);
    if(passes > 0){
        int RPP = BT / passes;
        int nmb = RPP / 64;
        int MBT = RPP / 32;
        for(int p = 0; p < passes; ++p){
            int row_off = p * RPP;
            ff1_kernel  <<<nmb*16, 256, 0, stream>>>(h1b, w1b, b_ff1, sblk, row_off, nmb, MBT);
            ff2_ln_kernel<<<MBT, 256, 0, stream>>>(sblk, w2b, b_ff2, h1,
                                                   ln2_g, ln2_b, lnf_g, lnf_b,
                                                   out, row_off, MBT);
        }
    } else {
        ff_fused_kernel<<<BT/64, 256, 0, stream>>>(h1b, h1, w1b, b_ff1, w2b, b_ff2, h2pre);
        ln2f_kernel    <<<BT/64, 256, 0, stream>>>(h2pre, ln2_g, ln2_b, lnf_g, lnf_b, out);
    }
}

// Round 7
// 151.780 us; speedup vs baseline: 5.6166x; 1.1507x over previous
//
#include <hip/hip_runtime.h>
#include <hip/hip_bf16.h>

#define B 8
#define T 2048
#define C 96
#define NH 3
#define HD 32
#define FFD 2048
#define HALF_W 32
#define BT (B*T)

typedef __hip_bfloat16 bf16;
typedef __attribute__((ext_vector_type(8))) short short8;
typedef __attribute__((ext_vector_type(4))) short short4v;
typedef __attribute__((ext_vector_type(16))) float floatx16;

__device__ __forceinline__ short f2bs(float v){
    __hip_bfloat16 h = __float2bfloat16(v);
    return *reinterpret_cast<short*>(&h);
}
__device__ __forceinline__ int imin(int a, int b){ return a < b ? a : b; }
__device__ __forceinline__ int imax(int a, int b){ return a > b ? a : b; }
__device__ __forceinline__ short8 ld_b64x2(const short* p){
    short4v a = *(const short4v*)p;
    short4v b = *(const short4v*)(p + 4);
    short8 v;
    v[0]=a[0]; v[1]=a[1]; v[2]=a[2]; v[3]=a[3];
    v[4]=b[0]; v[5]=b[1]; v[6]=b[2]; v[7]=b[3];
    return v;
}

// ---------------- K0: convert all weights to bf16 ----------------
__global__ void cvtw_kernel(const float* __restrict__ wq, const float* __restrict__ wo,
                            const float* __restrict__ w1, const float* __restrict__ w2,
                            bf16* __restrict__ dst){
    int i = blockIdx.x*256 + threadIdx.x;
    if(i < 27648)       dst[i] = __float2bfloat16(wq[i]);
    else if(i < 36864)  dst[i] = __float2bfloat16(wo[i-27648]);
    else if(i < 233472) dst[i] = __float2bfloat16(w1[i-36864]);
    else if(i < 430080) dst[i] = __float2bfloat16(w2[i-233472]);
}

// ---------------- K1: QKV projection, MFMA; Q/K/V stored [type][b][h][t][32] ----------------
__global__ __launch_bounds__(256) void qkv_kernel(
    const float* __restrict__ x, const bf16* __restrict__ wq,
    const float* __restrict__ bias, bf16* __restrict__ qkvs){
    __shared__ float xs[96*36];   // [c][t], stride 36 (conflict-free for frag build)
    int b  = blockIdx.x >> 6;            // T/32 = 64 tiles per batch
    int t0 = (blockIdx.x & 63) * 32;
    for(int e = threadIdx.x; e < 96*8; e += 256){
        int c = e >> 3, t4 = e & 7;
        *(float4*)(xs + c*36 + t4*4) =
            *(const float4*)(x + (size_t)b*C*T + (size_t)c*T + t0 + t4*4);
    }
    __syncthreads();
    int r0 = b*T + t0;
    const int w = threadIdx.x >> 6, lane = threadIdx.x & 63;
    const int lm = lane & 31, hq = lane >> 5;
    short8 bfr[6];
    #pragma unroll
    for(int ks = 0; ks < 6; ++ks){
        short8 v;
        #pragma unroll
        for(int i = 0; i < 8; ++i)
            v[i] = f2bs(xs[(ks*16 + hq*8 + i)*36 + lm]);
        bfr[ks] = v;
    }
    int nacc = (w == 0) ? 3 : 2;
    int ots[3] = {w, w+4, 8};
    floatx16 acc[3];
    #pragma unroll
    for(int i = 0; i < 3; ++i)
        #pragma unroll
        for(int r = 0; r < 16; ++r) acc[i][r] = 0.f;
    #pragma unroll
    for(int i = 0; i < 3; ++i){
        if(i < nacc){
            #pragma unroll
            for(int ks = 0; ks < 6; ++ks){
                short8 af = *(const short8*)((const short*)wq
                              + (size_t)(ots[i]*32 + lm)*96 + ks*16 + hq*8);
                acc[i] = __builtin_amdgcn_mfma_f32_32x32x16_bf16(af, bfr[ks], acc[i], 0,0,0);
            }
        }
    }
    // D: col=lm=token, reg->o_local. Store [type][b][h][t][32] (line-covered rows)
    #pragma unroll
    for(int i = 0; i < 3; ++i){
        if(i < nacc){
            int type = ots[i]/3, hh = ots[i]%3;
            size_t rowbase = (((size_t)type*B*NH) + (size_t)b*NH + hh)*T + t0 + lm;
            #pragma unroll
            for(int q = 0; q < 4; ++q){
                float4 bv = *(const float4*)(bias + ots[i]*32 + 8*q + 4*hq);
                short4v pk;
                pk[0] = f2bs(acc[i][4*q+0] + bv.x);
                pk[1] = f2bs(acc[i][4*q+1] + bv.y);
                pk[2] = f2bs(acc[i][4*q+2] + bv.z);
                pk[3] = f2bs(acc[i][4*q+3] + bv.w);
                *(short4v*)((short*)qkvs + rowbase*32 + 8*q + 4*hq) = pk;
            }
        }
    }
}

// ---------------- K2: banded attention via MFMA, 64-query blocks ----------------
__global__ __launch_bounds__(128) void attn_kernel(const bf16* __restrict__ qkvs,
                                                   bf16* __restrict__ ctxh){
    __shared__ __align__(16) short VtS[32*132];     // V^T [d][key 0..127]
    __shared__ __align__(16) short PtS[2][32*100];  // per wave: P [query][key 0..95]
    __shared__ float LsS[2][32];
    int blk = blockIdx.x;
    int ntile = T/64;  // 32
    int b   = blk / (NH*ntile);
    int rem = blk % (NH*ntile);
    int h   = rem / ntile;
    int t0  = (rem % ntile) * 64;
    const short* qb = (const short*)qkvs + ((size_t)0*B*NH + (size_t)b*NH + h)*T*32;
    const short* kb = (const short*)qkvs + ((size_t)1*B*NH + (size_t)b*NH + h)*T*32;
    const short* vb = (const short*)qkvs + ((size_t)2*B*NH + (size_t)b*NH + h)*T*32;
    const int tid = threadIdx.x;
    const int w = tid >> 6, lane = tid & 63;
    const int lm = lane & 31, hq = lane >> 5;

    for(int e = tid; e < 256; e += 128){
        int kp = e >> 2, d8 = e & 3;
        int sa = imin(imax(t0 - 32 + 2*kp, 0), T-1);
        int sb = imin(imax(t0 - 32 + 2*kp + 1, 0), T-1);
        short8 va = *(const short8*)(vb + (size_t)sa*32 + d8*8);
        short8 v2 = *(const short8*)(vb + (size_t)sb*32 + d8*8);
        #pragma unroll
        for(int j = 0; j < 8; ++j){
            int val = (int)(unsigned short)va[j] | ((int)(unsigned short)v2[j] << 16);
            *(int*)(VtS + (d8*8 + j)*132 + 2*kp) = val;
        }
    }
    short8 qf0, qf1;
    {
        const short* qrow = qb + (size_t)(t0 + 32*w + lm)*32;
        qf0 = *(const short8*)(qrow + hq*8);
        qf1 = *(const short8*)(qrow + 16 + hq*8);
    }
    floatx16 S[3];
    #pragma unroll
    for(int sub = 0; sub < 3; ++sub){
        int srow = imin(imax(t0 + 32*w - 32 + sub*32 + lm, 0), T-1);
        const short* krow = kb + (size_t)srow*32;
        short8 kf0 = *(const short8*)(krow + hq*8);
        short8 kf1 = *(const short8*)(krow + 16 + hq*8);
        floatx16 z;
        #pragma unroll
        for(int r = 0; r < 16; ++r) z[r] = 0.f;
        z = __builtin_amdgcn_mfma_f32_32x32x16_bf16(kf0, qf0, z, 0,0,0);
        z = __builtin_amdgcn_mfma_f32_32x32x16_bf16(kf1, qf1, z, 0,0,0);
        S[sub] = z;
    }
    const float scale = 0.17677669529663687f;
    float part = 0.f;
    #pragma unroll
    for(int sub = 0; sub < 3; ++sub){
        #pragma unroll
        for(int r = 0; r < 16; ++r){
            int key_local = sub*32 + (r&3) + 8*(r>>2) + 4*hq;
            int s_glob = t0 + 32*w - 32 + key_local;
            int rel = key_local - lm;
            bool ok = (rel >= 0) && (rel <= 64) && (s_glob >= 0) && (s_glob < T);
            float p = ok ? __expf(S[sub][r]*scale) : 0.f;
            S[sub][r] = p;
            part += p;
        }
    }
    float ltot = part + __shfl_xor(part, 32);
    if(hq == 0) LsS[w][lm] = ltot;
    #pragma unroll
    for(int sub = 0; sub < 3; ++sub){
        #pragma unroll
        for(int q4 = 0; q4 < 4; ++q4){
            int kbase = sub*32 + 8*q4 + 4*hq;
            short4v pk;
            pk[0] = f2bs(S[sub][4*q4+0]);
            pk[1] = f2bs(S[sub][4*q4+1]);
            pk[2] = f2bs(S[sub][4*q4+2]);
            pk[3] = f2bs(S[sub][4*q4+3]);
            *(short4v*)(PtS[w] + lm*100 + kbase) = pk;
        }
    }
    __syncthreads();
    floatx16 O;
    #pragma unroll
    for(int r = 0; r < 16; ++r) O[r] = 0.f;
    #pragma unroll
    for(int ks = 0; ks < 6; ++ks){
        short8 pa = ld_b64x2(PtS[w] + lm*100 + ks*16 + hq*8);
        short8 vf = ld_b64x2(VtS + lm*132 + 32*w + ks*16 + hq*8);
        O = __builtin_amdgcn_mfma_f32_32x32x16_bf16(pa, vf, O, 0,0,0);
    }
    #pragma unroll
    for(int r = 0; r < 16; ++r){
        int qr = (r&3) + 8*(r>>2) + 4*hq;
        float linv = 1.f / LsS[w][qr];
        ((short*)ctxh)[(((size_t)b*NH + h)*T + t0 + 32*w + qr)*32 + lm] = f2bs(O[r]*linv);
    }
}

// ---------------- K3: outproj + residual(x direct) + LN1 fused ----------------
__global__ __launch_bounds__(192) void outproj_ln_kernel(
    const bf16* __restrict__ ctxh, const bf16* __restrict__ wo,
    const float* __restrict__ bias, const float* __restrict__ x,
    const float* __restrict__ g1, const float* __restrict__ bb1,
    float* __restrict__ h1, bf16* __restrict__ h1b){
    __shared__ float red[2][3][32];
    const int ct = threadIdx.x >> 6, lane = threadIdx.x & 63;
    const int lm = lane & 31, hq = lane >> 5;
    const int r0 = blockIdx.x * 32;
    const int b = r0 / T, tloc = r0 % T;
    short8 bfr[6];
    #pragma unroll
    for(int ks = 0; ks < 6; ++ks){
        int off = ks*16 + hq*8;
        int hh = off >> 5, dd = off & 31;
        bfr[ks] = *(const short8*)((const short*)ctxh
                    + (((size_t)b*NH + hh)*T + tloc + lm)*32 + dd);
    }
    floatx16 acc;
    #pragma unroll
    for(int r = 0; r < 16; ++r) acc[r] = 0.f;
    #pragma unroll
    for(int ks = 0; ks < 6; ++ks){
        short8 af = *(const short8*)((const short*)wo
                      + (size_t)(ct*32 + lm)*96 + ks*16 + hq*8);
        acc = __builtin_amdgcn_mfma_f32_32x32x16_bf16(af, bfr[ks], acc, 0,0,0);
    }
    float vals[16];
    float p1 = 0.f, p2 = 0.f;
    #pragma unroll
    for(int q = 0; q < 4; ++q){
        int c = ct*32 + 8*q + 4*hq;
        float4 bv = *(const float4*)(bias + c);
        float bva[4] = {bv.x, bv.y, bv.z, bv.w};
        #pragma unroll
        for(int r = 0; r < 4; ++r){
            float xv = x[(size_t)b*C*T + (size_t)(c + r)*T + tloc + lm];
            float v = acc[4*q+r] + bva[r] + xv;
            vals[4*q+r] = v;
            p1 += v; p2 += v*v;
        }
    }
    p1 += __shfl_xor(p1, 32);
    p2 += __shfl_xor(p2, 32);
    if(hq == 0){ red[0][ct][lm] = p1; red[1][ct][lm] = p2; }
    __syncthreads();
    float s  = red[0][0][lm] + red[0][1][lm] + red[0][2][lm];
    float s2 = red[1][0][lm] + red[1][1][lm] + red[1][2][lm];
    float mu = s * (1.0f/96.0f);
    float rstd = rsqrtf(s2*(1.0f/96.0f) - mu*mu + 1e-5f);
    int row = r0 + lm;
    #pragma unroll
    for(int q = 0; q < 4; ++q){
        int c = ct*32 + 8*q + 4*hq;
        float4 gv = *(const float4*)(g1 + c);
        float4 bv = *(const float4*)(bb1 + c);
        float ga[4] = {gv.x, gv.y, gv.z, gv.w};
        float ba[4] = {bv.x, bv.y, bv.z, bv.w};
        float4 yo;
        float ya[4];
        #pragma unroll
        for(int r = 0; r < 4; ++r)
            ya[r] = (vals[4*q+r] - mu)*rstd*ga[r] + ba[r];
        yo.x = ya[0]; yo.y = ya[1]; yo.z = ya[2]; yo.w = ya[3];
        *(float4*)(h1 + (size_t)row*96 + c) = yo;
        short4v pk;
        #pragma unroll
        for(int r = 0; r < 4; ++r) pk[r] = f2bs(ya[r]);
        *(short4v*)((short*)h1b + (size_t)row*96 + c) = pk;
    }
}

// ---------------- K4: fused FF, barrier-free j-loop + LN2/LNf/transpose-out ----------------
// grid BT/32 = 512, block 256. Wave w: FF1 j-cols [32w,32w+32) over all 32 rows,
// FF2 k-groups {2w,2w+1} — S round-trip through LDS is wave-private (no barriers).
// acc2[3ct] holds the wave's K-partition partial; epilogue reduces across waves.
__global__ __launch_bounds__(256) void ff_ln_kernel(
    const bf16* __restrict__ h1b, const float* __restrict__ h1,
    const bf16* __restrict__ w1b, const float* __restrict__ b1,
    const bf16* __restrict__ w2b, const float* __restrict__ b2,
    const float* __restrict__ g2, const float* __restrict__ bt2,
    const float* __restrict__ gf, const float* __restrict__ btf,
    float* __restrict__ out){
    __shared__ __align__(16) short sst[32*132];   // S [m][j-local 0..127], 2-way-free stride
    __shared__ float redp[9*1088];                // waves 1..3 partials, stride-17 padded
    __shared__ float zt[96*33];                   // LN output transposed
    const int tid = threadIdx.x;
    const int w = tid >> 6, lane = tid & 63;
    const int lm = lane & 31, hq = lane >> 5;
    const int r0 = blockIdx.x * 32;
    short8 hf[6];
    #pragma unroll
    for(int ks = 0; ks < 6; ++ks)
        hf[ks] = *(const short8*)((const short*)h1b
                   + (size_t)(r0 + lm)*96 + ks*16 + hq*8);
    floatx16 acc2[3];
    #pragma unroll
    for(int i = 0; i < 3; ++i)
        #pragma unroll
        for(int r = 0; r < 16; ++r) acc2[i][r] = 0.f;
    for(int jt = 0; jt < 16; ++jt){
        const int j0 = jt * 128;
        // FF1: A = w1 rows (j), B = hf. D[j][m]: col=lm=m, reg->j-local.
        floatx16 a0;
        #pragma unroll
        for(int r = 0; r < 16; ++r) a0[r] = 0.f;
        #pragma unroll
        for(int ks = 0; ks < 6; ++ks){
            short8 af = *(const short8*)((const short*)w1b
                          + (size_t)(j0 + w*32 + lm)*96 + ks*16 + hq*8);
            a0 = __builtin_amdgcn_mfma_f32_32x32x16_bf16(af, hf[ks], a0, 0,0,0);
        }
        // bias + relu + pack to wave-private sst columns [32w, 32w+32)
        #pragma unroll
        for(int q = 0; q < 4; ++q){
            float4 bv = *(const float4*)(b1 + j0 + w*32 + 8*q + 4*hq);
            float bva[4] = {bv.x, bv.y, bv.z, bv.w};
            short4v pk;
            #pragma unroll
            for(int r = 0; r < 4; ++r){
                float v = a0[4*q+r] + bva[r];
                pk[r] = f2bs(v > 0.f ? v : 0.f);
            }
            *(short4v*)(sst + lm*132 + w*32 + 8*q + 4*hq) = pk;
        }
        // FF2: wave-private k-groups; A = w2 rows (c), B = sst rows (m).
        #pragma unroll
        for(int g = 0; g < 2; ++g){
            int jl0 = w*32 + g*16;
            short8 sf = ld_b64x2(sst + lm*132 + jl0 + hq*8);
            #pragma unroll
            for(int ct = 0; ct < 3; ++ct){
                short8 wf = *(const short8*)((const short*)w2b
                              + (size_t)(ct*32 + lm)*FFD + j0 + jl0 + hq*8);
                acc2[ct] = __builtin_amdgcn_mfma_f32_32x32x16_bf16(wf, sf, acc2[ct], 0,0,0);
            }
        }
    }
    // ---- epilogue: cross-wave reduce + b2 + residual + LN2 + LNf + transpose out
    __syncthreads();
    if(w > 0){
        #pragma unroll
        for(int ct = 0; ct < 3; ++ct)
            #pragma unroll
            for(int q = 0; q < 4; ++q)
                #pragma unroll
                for(int r = 0; r < 4; ++r)
                    redp[((w-1)*3 + ct)*1088 + lane*17 + 4*q + r] = acc2[ct][4*q+r];
    }
    __syncthreads();
    if(w == 0){
        float vals[48];
        float p1 = 0.f, p2 = 0.f;
        #pragma unroll
        for(int ct = 0; ct < 3; ++ct){
            #pragma unroll
            for(int q = 0; q < 4; ++q){
                int c = ct*32 + 8*q + 4*hq;
                float4 bv = *(const float4*)(b2 + c);
                float4 rs = *(const float4*)(h1 + (size_t)(r0 + lm)*96 + c);
                float bva[4] = {bv.x, bv.y, bv.z, bv.w};
                float rsa[4] = {rs.x, rs.y, rs.z, rs.w};
                #pragma unroll
                for(int r = 0; r < 4; ++r){
                    float v = acc2[ct][4*q+r]
                            + redp[(0*3 + ct)*1088 + lane*17 + 4*q + r]
                            + redp[(1*3 + ct)*1088 + lane*17 + 4*q + r]
                            + redp[(2*3 + ct)*1088 + lane*17 + 4*q + r]
                            + bva[r] + rsa[r];
                    vals[ct*16 + 4*q + r] = v;
                    p1 += v; p2 += v*v;
                }
            }
        }
        p1 += __shfl_xor(p1, 32);
        p2 += __shfl_xor(p2, 32);
        float mu = p1*(1.0f/96.0f);
        float rstd = rsqrtf(p2*(1.0f/96.0f) - mu*mu + 1e-5f);
        float q1 = 0.f, q2 = 0.f;
        #pragma unroll
        for(int ct = 0; ct < 3; ++ct){
            #pragma unroll
            for(int q = 0; q < 4; ++q){
                int c = ct*32 + 8*q + 4*hq;
                float4 gv = *(const float4*)(g2 + c);
                float4 bv = *(const float4*)(bt2 + c);
                float ga[4] = {gv.x, gv.y, gv.z, gv.w};
                float ba[4] = {bv.x, bv.y, bv.z, bv.w};
                #pragma unroll
                for(int r = 0; r < 4; ++r){
                    float y = (vals[ct*16+4*q+r] - mu)*rstd*ga[r] + ba[r];
                    vals[ct*16+4*q+r] = y;
                    q1 += y; q2 += y*y;
                }
            }
        }
        q1 += __shfl_xor(q1, 32);
        q2 += __shfl_xor(q2, 32);
        float mu2 = q1*(1.0f/96.0f);
        float rstd2 = rsqrtf(q2*(1.0f/96.0f) - mu2*mu2 + 1e-5f);
        #pragma unroll
        for(int ct = 0; ct < 3; ++ct){
            #pragma unroll
            for(int q = 0; q < 4; ++q){
                int c = ct*32 + 8*q + 4*hq;
                float4 gv = *(const float4*)(gf + c);
                float4 bv = *(const float4*)(btf + c);
                float ga[4] = {gv.x, gv.y, gv.z, gv.w};
                float ba[4] = {bv.x, bv.y, bv.z, bv.w};
                #pragma unroll
                for(int r = 0; r < 4; ++r)
                    zt[(c + r)*33 + lm] = (vals[ct*16+4*q+r] - mu2)*rstd2*ga[r] + ba[r];
            }
        }
    }
    __syncthreads();
    int bb  = r0 / T;
    int t0g = r0 % T;
    for(int e = tid; e < 96*32; e += 256){
        int c = e >> 5, tt = e & 31;
        out[(size_t)bb*C*T + (size_t)c*T + t0g + tt] = zt[c*33 + tt];
    }
}

extern "C" void kernel_launch(void* const* d_in, const int* in_sizes, int n_in,
                              void* d_out, int out_size, void* d_ws, size_t ws_size,
                              hipStream_t stream) {
    const float* x     = (const float*)d_in[0];
    const float* w_qkv = (const float*)d_in[1];
    const float* b_qkv = (const float*)d_in[2];
    const float* w_out = (const float*)d_in[3];
    const float* b_out = (const float*)d_in[4];
    const float* ln1_g = (const float*)d_in[5];
    const float* ln1_b = (const float*)d_in[6];
    const float* w_ff1 = (const float*)d_in[7];
    const float* b_ff1 = (const float*)d_in[8];
    const float* w_ff2 = (const float*)d_in[9];
    const float* b_ff2 = (const float*)d_in[10];
    const float* ln2_g = (const float*)d_in[11];
    const float* ln2_b = (const float*)d_in[12];
    const float* lnf_g = (const float*)d_in[13];
    const float* lnf_b = (const float*)d_in[14];
    float* out = (float*)d_out;

    // ws map (bytes), total 22.9 MB:
    //   qkvs [0, 9.44M)         Q/K/V [type][b][h][t][32] bf16
    //   ctxh [9.44M, 12.58M)    ctx [b][h][t][32] bf16
    //   h1   [12.58M, 18.87M)   fp32 LN1 output
    //   h1b  [18.87M, 22.02M)   bf16 LN1 output
    //   wts  [22.02M, 22.88M)   bf16 weights
    char* wsb = (char*)d_ws;
    bf16*  qkvs  = (bf16*)wsb;
    bf16*  ctxh  = (bf16*)(wsb + 9437184);
    float* h1    = (float*)(wsb + 12582912);
    bf16*  h1b   = (bf16*)(wsb + 18874368);
    bf16*  wts   = (bf16*)(wsb + 22020096);
    bf16*  wqkvb = wts;
    bf16*  woutb = wts + 27648;
    bf16*  w1b   = wts + 36864;
    bf16*  w2b   = wts + 233472;

    cvtw_kernel      <<<1680, 256, 0, stream>>>(w_qkv, w_out, w_ff1, w_ff2, wts);
    qkv_kernel       <<<BT/32, 256, 0, stream>>>(x, wqkvb, b_qkv, qkvs);
    attn_kernel      <<<B*NH*(T/64), 128, 0, stream>>>(qkvs, ctxh);
    outproj_ln_kernel<<<BT/32, 192, 0, stream>>>(ctxh, woutb, b_out, x,
                                                 ln1_g, ln1_b, h1, h1b);
    ff_ln_kernel     <<<BT/32, 256, 0, stream>>>(h1b, h1, w1b, b_ff1, w2b, b_ff2,
                                                 ln2_g, ln2_b, lnf_g, lnf_b, out);
}